// Round 1
// baseline (637.858 us; speedup 1.0000x reference)
//
#include <hip/hip_runtime.h>

#define N_NODES 50000
#define E_EDGES 800000
#define ET (E_EDGES + N_NODES)
#define C1 128
#define NCLASS 32

__device__ __forceinline__ float lrelu(float v) { return v > 0.f ? v : 0.2f * v; }

// ---------------- GEMM1: h1[N,128] = x[N,256] @ W1^T (W1 is [128,256]) ----------------
__global__ __launch_bounds__(256) void gemm1_kernel(const float* __restrict__ x,
                                                    const float* __restrict__ W1,
                                                    float* __restrict__ h1) {
    __shared__ float As[64][33];
    __shared__ float Wl[128][33];
    int t = threadIdx.x;
    int rb = blockIdx.x * 64;
    int ty = t >> 4, tx = t & 15;
    float acc[4][8];
#pragma unroll
    for (int i = 0; i < 4; i++)
#pragma unroll
        for (int j = 0; j < 8; j++) acc[i][j] = 0.f;

    for (int k0 = 0; k0 < 256; k0 += 32) {
#pragma unroll
        for (int i = 0; i < 8; i++) {
            int row = i * 8 + (t >> 5), kk = t & 31;
            int gr = rb + row;
            As[row][kk] = (gr < N_NODES) ? x[gr * 256 + k0 + kk] : 0.f;
        }
#pragma unroll
        for (int i = 0; i < 16; i++) {
            int c = i * 8 + (t >> 5), kk = t & 31;
            Wl[c][kk] = W1[c * 256 + k0 + kk];
        }
        __syncthreads();
#pragma unroll
        for (int kk = 0; kk < 32; kk++) {
            float a[4], b[8];
#pragma unroll
            for (int i = 0; i < 4; i++) a[i] = As[ty * 4 + i][kk];
#pragma unroll
            for (int j = 0; j < 8; j++) b[j] = Wl[tx * 8 + j][kk];
#pragma unroll
            for (int i = 0; i < 4; i++)
#pragma unroll
                for (int j = 0; j < 8; j++) acc[i][j] += a[i] * b[j];
        }
        __syncthreads();
    }
#pragma unroll
    for (int i = 0; i < 4; i++) {
        int gr = rb + ty * 4 + i;
        if (gr < N_NODES) {
#pragma unroll
            for (int j = 0; j < 8; j++) h1[gr * 128 + tx * 8 + j] = acc[i][j];
        }
    }
}

// ---------------- asc1/adc1: per-node per-head attention dots ----------------
__global__ __launch_bounds__(256) void ascadc1_kernel(const float* __restrict__ h1,
                                                      const float* __restrict__ as1,
                                                      const float* __restrict__ ad1,
                                                      float* __restrict__ asc1,
                                                      float* __restrict__ adc1) {
    int wid = threadIdx.x >> 6, lane = threadIdx.x & 63;
    int node = blockIdx.x * 4 + wid;
    if (node >= N_NODES) return;
    float v0 = h1[node * 128 + lane];
    float v1 = h1[node * 128 + 64 + lane];
    int hg = lane >> 5;   // head for channel c0=lane is hg; for c1=lane+64 is 2+hg
    int cc = lane & 31;
    float s0 = v0 * as1[hg * 32 + cc];
    float s1 = v1 * as1[(2 + hg) * 32 + cc];
    float d0 = v0 * ad1[hg * 32 + cc];
    float d1 = v1 * ad1[(2 + hg) * 32 + cc];
#pragma unroll
    for (int msk = 16; msk >= 1; msk >>= 1) {
        s0 += __shfl_xor(s0, msk);
        s1 += __shfl_xor(s1, msk);
        d0 += __shfl_xor(d0, msk);
        d1 += __shfl_xor(d1, msk);
    }
    if (cc == 0) {
        asc1[node * 4 + hg] = s0;
        asc1[node * 4 + 2 + hg] = s1;
        adc1[node * 4 + hg] = d0;
        adc1[node * 4 + 2 + hg] = d1;
    }
}

// ---------------- CSR build ----------------
__global__ void hist_kernel(const int* __restrict__ ei, int* __restrict__ deg) {
    int i = blockIdx.x * blockDim.x + threadIdx.x;
    if (i < E_EDGES) atomicAdd(&deg[ei[E_EDGES + i]], 1);
}

__global__ __launch_bounds__(1024) void scan_kernel(const int* __restrict__ deg,
                                                    int* __restrict__ off,
                                                    int* __restrict__ cursor) {
    __shared__ int sums[1024];
    int t = threadIdx.x;
    const int chunk = 49;  // 1024*49 >= 50000
    int s0 = t * chunk;
    int s1 = s0 + chunk;
    if (s1 > N_NODES) s1 = N_NODES;
    int local = 0;
    for (int n = s0; n < s1; n++) local += deg[n] + 1;  // +1 self loop
    sums[t] = local;
    __syncthreads();
    for (int d = 1; d < 1024; d <<= 1) {
        int v = (t >= d) ? sums[t - d] : 0;
        __syncthreads();
        sums[t] += v;
        __syncthreads();
    }
    int run = sums[t] - local;  // exclusive prefix
    for (int n = s0; n < s1; n++) {
        off[n] = run;
        cursor[n] = run;
        run += deg[n] + 1;
    }
    if (t == 1023) off[N_NODES] = run;
}

__global__ void fill_kernel(const int* __restrict__ ei, int* __restrict__ cursor,
                            int* __restrict__ csr) {
    int i = blockIdx.x * blockDim.x + threadIdx.x;
    if (i < E_EDGES) {
        int s = ei[i], d = ei[E_EDGES + i];
        int pos = atomicAdd(&cursor[d], 1);
        csr[pos] = s;
    } else if (i < ET) {
        int n = i - E_EDGES;
        int pos = atomicAdd(&cursor[n], 1);
        csr[pos] = n;
    }
}

// ---------------- Layer-1 aggregation (wave per dst node) ----------------
__global__ __launch_bounds__(256) void agg1_kernel(const float* __restrict__ h1,
                                                   const float* __restrict__ asc1,
                                                   const float* __restrict__ adc1,
                                                   const float* __restrict__ b1,
                                                   const int* __restrict__ off,
                                                   const int* __restrict__ csr,
                                                   float* __restrict__ h1b) {
    int wid = threadIdx.x >> 6, lane = threadIdx.x & 63;
    int node = blockIdx.x * 4 + wid;
    if (node >= N_NODES) return;
    int h0 = lane >> 5;   // head of channel c0=lane
    int h1h = 2 + h0;     // head of channel c1=lane+64
    float adA = adc1[node * 4 + h0];
    float adB = adc1[node * 4 + h1h];
    int s0 = off[node], s1 = off[node + 1];
    float m0 = -1e30f, m1 = -1e30f;
    for (int j = s0; j < s1; j++) {
        int s = csr[j];
        m0 = fmaxf(m0, lrelu(asc1[s * 4 + h0] + adA));
        m1 = fmaxf(m1, lrelu(asc1[s * 4 + h1h] + adB));
    }
    float d0 = 0.f, d1 = 0.f, a0 = 0.f, a1 = 0.f;
    for (int j = s0; j < s1; j++) {
        int s = csr[j];
        float p0 = __expf(lrelu(asc1[s * 4 + h0] + adA) - m0);
        float p1 = __expf(lrelu(asc1[s * 4 + h1h] + adB) - m1);
        d0 += p0;
        d1 += p1;
        a0 += p0 * h1[s * 128 + lane];
        a1 += p1 * h1[s * 128 + 64 + lane];
    }
    float o0 = a0 / (d0 + 1e-16f) + b1[lane];
    float o1 = a1 / (d1 + 1e-16f) + b1[64 + lane];
    h1b[node * 128 + lane] = fmaxf(o0, 0.f);
    h1b[node * 128 + 64 + lane] = fmaxf(o1, 0.f);
}

// ---------------- GEMM2 (+ asc2/adc2 epilogue): h2[N,32] = h1b @ W2^T ----------------
__global__ __launch_bounds__(256) void gemm2_kernel(const float* __restrict__ h1b,
                                                    const float* __restrict__ W2,
                                                    const float* __restrict__ as2,
                                                    const float* __restrict__ ad2,
                                                    float* __restrict__ h2,
                                                    float* __restrict__ asc2,
                                                    float* __restrict__ adc2) {
    __shared__ float Ws[128][33];
    __shared__ float Hs[8][128];
    int t = threadIdx.x;
#pragma unroll
    for (int i = 0; i < 16; i++) {
        int idx = i * 256 + t;
        int k = idx & 127, c = idx >> 7;
        Ws[k][c] = W2[c * 128 + k];
    }
    int rb = blockIdx.x * 8;
#pragma unroll
    for (int i = 0; i < 4; i++) {
        int idx = i * 256 + t;
        int rl = idx >> 7, k = idx & 127;
        int gr = rb + rl;
        Hs[rl][k] = (gr < N_NODES) ? h1b[gr * 128 + k] : 0.f;
    }
    __syncthreads();
    int rl = t >> 5, c = t & 31;
    int node = rb + rl;
    float acc = 0.f;
#pragma unroll
    for (int k = 0; k < 128; k++) acc += Hs[rl][k] * Ws[k][c];
    if (node < N_NODES) h2[node * 32 + c] = acc;
    float sv = acc * as2[c];
    float dv = acc * ad2[c];
#pragma unroll
    for (int msk = 16; msk >= 1; msk >>= 1) {
        sv += __shfl_xor(sv, msk);
        dv += __shfl_xor(dv, msk);
    }
    if (c == 0 && node < N_NODES) {
        asc2[node] = sv;
        adc2[node] = dv;
    }
}

// ---------------- Layer-2 aggregation + log_softmax (wave per dst node) ----------------
__global__ __launch_bounds__(256) void agg2_kernel(const float* __restrict__ h2,
                                                   const float* __restrict__ asc2,
                                                   const float* __restrict__ adc2,
                                                   const float* __restrict__ b2,
                                                   const int* __restrict__ off,
                                                   const int* __restrict__ csr,
                                                   float* __restrict__ out) {
    int wid = threadIdx.x >> 6, lane = threadIdx.x & 63;
    int node = blockIdx.x * 4 + wid;
    if (node >= N_NODES) return;
    int l32 = lane & 31, half = lane >> 5;
    float adv = adc2[node];
    int s0 = off[node], s1 = off[node + 1];
    float m = -1e30f;
    for (int j = s0; j < s1; j++) m = fmaxf(m, lrelu(asc2[csr[j]] + adv));
    float den = 0.f, acc = 0.f;
    for (int j = s0 + half; j < s1; j += 2) {
        int s = csr[j];
        float p = __expf(lrelu(asc2[s] + adv) - m);
        den += p;
        acc += p * h2[s * 32 + l32];
    }
    acc += __shfl_xor(acc, 32);
    den += __shfl_xor(den, 32);
    float v = acc / (den + 1e-16f) + b2[l32];
    float mx = v;
#pragma unroll
    for (int msk = 16; msk >= 1; msk >>= 1) mx = fmaxf(mx, __shfl_xor(mx, msk));
    float se = __expf(v - mx);
#pragma unroll
    for (int msk = 16; msk >= 1; msk >>= 1) se += __shfl_xor(se, msk);
    float o = v - mx - __logf(se);
    if (lane < 32) out[node * 32 + l32] = o;
}

extern "C" void kernel_launch(void* const* d_in, const int* in_sizes, int n_in,
                              void* d_out, int out_size, void* d_ws, size_t ws_size,
                              hipStream_t stream) {
    const float* x  = (const float*)d_in[0];
    const int* ei   = (const int*)d_in[1];
    const float* W1 = (const float*)d_in[2];
    const float* as1 = (const float*)d_in[3];
    const float* ad1 = (const float*)d_in[4];
    const float* b1 = (const float*)d_in[5];
    const float* W2 = (const float*)d_in[6];
    const float* as2 = (const float*)d_in[7];
    const float* ad2 = (const float*)d_in[8];
    const float* b2 = (const float*)d_in[9];
    float* out = (float*)d_out;

    float* ws = (float*)d_ws;
    float* h1   = ws;
    float* h1b  = h1 + (size_t)N_NODES * C1;
    float* h2   = h1b + (size_t)N_NODES * C1;
    float* asc1 = h2 + (size_t)N_NODES * NCLASS;
    float* adc1 = asc1 + (size_t)N_NODES * 4;
    float* asc2 = adc1 + (size_t)N_NODES * 4;
    float* adc2 = asc2 + (size_t)N_NODES;
    int* deg    = (int*)(adc2 + (size_t)N_NODES);
    int* off    = deg + N_NODES;
    int* cursor = off + (N_NODES + 1);
    int* csr    = cursor + (N_NODES + 1);

    hipMemsetAsync(deg, 0, N_NODES * sizeof(int), stream);

    gemm1_kernel<<<(N_NODES + 63) / 64, 256, 0, stream>>>(x, W1, h1);
    ascadc1_kernel<<<(N_NODES + 3) / 4, 256, 0, stream>>>(h1, as1, ad1, asc1, adc1);
    hist_kernel<<<(E_EDGES + 255) / 256, 256, 0, stream>>>(ei, deg);
    scan_kernel<<<1, 1024, 0, stream>>>(deg, off, cursor);
    fill_kernel<<<(ET + 255) / 256, 256, 0, stream>>>(ei, cursor, csr);
    agg1_kernel<<<(N_NODES + 3) / 4, 256, 0, stream>>>(h1, asc1, adc1, b1, off, csr, h1b);
    gemm2_kernel<<<(N_NODES + 7) / 8, 256, 0, stream>>>(h1b, W2, as2, ad2, h2, asc2, adc2);
    agg2_kernel<<<(N_NODES + 3) / 4, 256, 0, stream>>>(h2, asc2, adc2, b2, off, csr, out);
}

// Round 2
// 454.186 us; speedup vs baseline: 1.4044x; 1.4044x over previous
//
#include <hip/hip_runtime.h>
#include <hip/hip_fp16.h>

#define N_NODES 50000
#define E_EDGES 800000
#define ET (E_EDGES + N_NODES)
#define C1 128
#define NCLASS 32

__device__ __forceinline__ float lrelu(float v) { return v > 0.f ? v : 0.2f * v; }

// ---------------- GEMM1: h1h[N,128](fp16) = x[N,256] @ W1^T (W1 is [128,256]) ----------------
__global__ __launch_bounds__(256) void gemm1_kernel(const float* __restrict__ x,
                                                    const float* __restrict__ W1,
                                                    __half* __restrict__ h1h) {
    __shared__ float As[64][33];
    __shared__ float Wl[128][33];
    int t = threadIdx.x;
    int rb = blockIdx.x * 64;
    int ty = t >> 4, tx = t & 15;
    float acc[4][8];
#pragma unroll
    for (int i = 0; i < 4; i++)
#pragma unroll
        for (int j = 0; j < 8; j++) acc[i][j] = 0.f;

    for (int k0 = 0; k0 < 256; k0 += 32) {
#pragma unroll
        for (int i = 0; i < 8; i++) {
            int row = i * 8 + (t >> 5), kk = t & 31;
            int gr = rb + row;
            As[row][kk] = (gr < N_NODES) ? x[gr * 256 + k0 + kk] : 0.f;
        }
#pragma unroll
        for (int i = 0; i < 16; i++) {
            int c = i * 8 + (t >> 5), kk = t & 31;
            Wl[c][kk] = W1[c * 256 + k0 + kk];
        }
        __syncthreads();
#pragma unroll
        for (int kk = 0; kk < 32; kk++) {
            float a[4], b[8];
#pragma unroll
            for (int i = 0; i < 4; i++) a[i] = As[ty * 4 + i][kk];
#pragma unroll
            for (int j = 0; j < 8; j++) b[j] = Wl[tx * 8 + j][kk];
#pragma unroll
            for (int i = 0; i < 4; i++)
#pragma unroll
                for (int j = 0; j < 8; j++) acc[i][j] += a[i] * b[j];
        }
        __syncthreads();
    }
    __half2* h1h2 = (__half2*)h1h;
#pragma unroll
    for (int i = 0; i < 4; i++) {
        int gr = rb + ty * 4 + i;
        if (gr < N_NODES) {
#pragma unroll
            for (int j = 0; j < 8; j += 2) {
                h1h2[gr * 64 + (tx * 8 + j) / 2] = __floats2half2_rn(acc[i][j], acc[i][j + 1]);
            }
        }
    }
}

// ---------------- asc1/adc1: per-node per-head attention dots (from fp16 h1) ----------------
__global__ __launch_bounds__(256) void ascadc1_kernel(const __half* __restrict__ h1h,
                                                      const float* __restrict__ as1,
                                                      const float* __restrict__ ad1,
                                                      float* __restrict__ asc1,
                                                      float* __restrict__ adc1) {
    int wid = threadIdx.x >> 6, lane = threadIdx.x & 63;
    int node = blockIdx.x * 4 + wid;
    if (node >= N_NODES) return;
    const __half2* h1h2 = (const __half2*)h1h;
    float2 f = __half22float2(h1h2[node * 64 + lane]);   // channels 2l, 2l+1
    int hh = lane >> 4;                 // head
    int ci = (lane & 15) * 2;           // channel within head
    float s = f.x * as1[hh * 32 + ci] + f.y * as1[hh * 32 + ci + 1];
    float d = f.x * ad1[hh * 32 + ci] + f.y * ad1[hh * 32 + ci + 1];
#pragma unroll
    for (int msk = 8; msk >= 1; msk >>= 1) {
        s += __shfl_xor(s, msk);
        d += __shfl_xor(d, msk);
    }
    if ((lane & 15) == 0) {
        asc1[node * 4 + hh] = s;
        adc1[node * 4 + hh] = d;
    }
}

// ---------------- CSR build ----------------
__global__ void hist_kernel(const int* __restrict__ ei, int* __restrict__ deg) {
    int i = blockIdx.x * blockDim.x + threadIdx.x;
    if (i < E_EDGES) atomicAdd(&deg[ei[E_EDGES + i]], 1);
}

__global__ __launch_bounds__(1024) void scan_kernel(const int* __restrict__ deg,
                                                    int* __restrict__ off,
                                                    int* __restrict__ cursor) {
    __shared__ int sums[1024];
    int t = threadIdx.x;
    const int chunk = 49;  // 1024*49 >= 50000
    int s0 = t * chunk;
    int s1 = s0 + chunk;
    if (s1 > N_NODES) s1 = N_NODES;
    if (s0 > N_NODES) s0 = N_NODES;
    int local = 0;
    for (int n = s0; n < s1; n++) local += deg[n] + 1;  // +1 self loop
    sums[t] = local;
    __syncthreads();
    for (int d = 1; d < 1024; d <<= 1) {
        int v = (t >= d) ? sums[t - d] : 0;
        __syncthreads();
        sums[t] += v;
        __syncthreads();
    }
    int run = sums[t] - local;  // exclusive prefix
    for (int n = s0; n < s1; n++) {
        off[n] = run;
        cursor[n] = run;
        run += deg[n] + 1;
    }
    if (t == 1023) off[N_NODES] = run;
}

// fill CSR + per-edge layer-1 logits e1[pos][4] (CSR order)
__global__ void fill_kernel(const int* __restrict__ ei, int* __restrict__ cursor,
                            const float* __restrict__ asc1, const float* __restrict__ adc1,
                            int* __restrict__ csr, int* __restrict__ dpos,
                            float* __restrict__ e1) {
    int i = blockIdx.x * blockDim.x + threadIdx.x;
    if (i >= ET) return;
    int s, d;
    if (i < E_EDGES) { s = ei[i]; d = ei[E_EDGES + i]; }
    else { s = i - E_EDGES; d = s; }
    int pos = atomicAdd(&cursor[d], 1);
    csr[pos] = s;
    dpos[pos] = d;
    float4 av = *(const float4*)(asc1 + s * 4);
    float4 dv = *(const float4*)(adc1 + d * 4);
    float4 e;
    e.x = lrelu(av.x + dv.x);
    e.y = lrelu(av.y + dv.y);
    e.z = lrelu(av.z + dv.z);
    e.w = lrelu(av.w + dv.w);
    *(float4*)(e1 + (size_t)pos * 4) = e;
}

// ---------------- Layer-1 aggregation (wave per dst node) ----------------
__global__ __launch_bounds__(256) void agg1_kernel(const __half* __restrict__ h1h,
                                                   const float* __restrict__ e1,
                                                   const float* __restrict__ b1,
                                                   const int* __restrict__ off,
                                                   const int* __restrict__ csr,
                                                   float* __restrict__ h1b) {
    int wid = threadIdx.x >> 6, lane = threadIdx.x & 63;
    int node = blockIdx.x * 4 + wid;
    if (node >= N_NODES) return;
    int hh = lane >> 4;  // head of channels 2l,2l+1
    const __half2* h1h2 = (const __half2*)h1h;
    int s0 = off[node], s1 = off[node + 1];
    // pass 1: max over this node's edges (sequential, L1-resident)
    float m = -1e30f;
    int j = s0;
    for (; j + 4 <= s1; j += 4) {
        float a0 = e1[(size_t)(j + 0) * 4 + hh];
        float a1 = e1[(size_t)(j + 1) * 4 + hh];
        float a2 = e1[(size_t)(j + 2) * 4 + hh];
        float a3 = e1[(size_t)(j + 3) * 4 + hh];
        m = fmaxf(fmaxf(fmaxf(m, a0), a1), fmaxf(a2, a3));
    }
    for (; j < s1; j++) m = fmaxf(m, e1[(size_t)j * 4 + hh]);
    // pass 2: denom + weighted sum (gather fp16 rows, unroll 4 for MLP)
    float den = 0.f, acc0 = 0.f, acc1 = 0.f;
    j = s0;
    for (; j + 4 <= s1; j += 4) {
        int sA = csr[j], sB = csr[j + 1], sC = csr[j + 2], sD = csr[j + 3];
        float eA = e1[(size_t)(j + 0) * 4 + hh];
        float eB = e1[(size_t)(j + 1) * 4 + hh];
        float eC = e1[(size_t)(j + 2) * 4 + hh];
        float eD = e1[(size_t)(j + 3) * 4 + hh];
        __half2 hA = h1h2[(size_t)sA * 64 + lane];
        __half2 hB = h1h2[(size_t)sB * 64 + lane];
        __half2 hC = h1h2[(size_t)sC * 64 + lane];
        __half2 hD = h1h2[(size_t)sD * 64 + lane];
        float pA = __expf(eA - m), pB = __expf(eB - m), pC = __expf(eC - m), pD = __expf(eD - m);
        den += (pA + pB) + (pC + pD);
        float2 fA = __half22float2(hA), fB = __half22float2(hB);
        float2 fC = __half22float2(hC), fD = __half22float2(hD);
        acc0 += pA * fA.x + pB * fB.x + pC * fC.x + pD * fD.x;
        acc1 += pA * fA.y + pB * fB.y + pC * fC.y + pD * fD.y;
    }
    for (; j < s1; j++) {
        int s = csr[j];
        float p = __expf(e1[(size_t)j * 4 + hh] - m);
        float2 f = __half22float2(h1h2[(size_t)s * 64 + lane]);
        den += p;
        acc0 += p * f.x;
        acc1 += p * f.y;
    }
    float inv = 1.f / (den + 1e-16f);
    float o0 = fmaxf(acc0 * inv + b1[2 * lane], 0.f);
    float o1 = fmaxf(acc1 * inv + b1[2 * lane + 1], 0.f);
    ((float2*)h1b)[(size_t)node * 64 + lane] = make_float2(o0, o1);
}

// ---------------- GEMM2 (+ asc2/adc2 epilogue): h2h[N,32](fp16) = h1b @ W2^T ----------------
__global__ __launch_bounds__(256) void gemm2_kernel(const float* __restrict__ h1b,
                                                    const float* __restrict__ W2,
                                                    const float* __restrict__ as2,
                                                    const float* __restrict__ ad2,
                                                    __half* __restrict__ h2h,
                                                    float* __restrict__ asc2,
                                                    float* __restrict__ adc2) {
    __shared__ float Ws[128][33];
    __shared__ float Hs[8][128];
    int t = threadIdx.x;
#pragma unroll
    for (int i = 0; i < 16; i++) {
        int idx = i * 256 + t;
        int k = idx & 127, c = idx >> 7;
        Ws[k][c] = W2[c * 128 + k];
    }
    int rb = blockIdx.x * 8;
#pragma unroll
    for (int i = 0; i < 4; i++) {
        int idx = i * 256 + t;
        int rl = idx >> 7, k = idx & 127;
        int gr = rb + rl;
        Hs[rl][k] = (gr < N_NODES) ? h1b[(size_t)gr * 128 + k] : 0.f;
    }
    __syncthreads();
    int rl = t >> 5, c = t & 31;
    int node = rb + rl;
    float acc = 0.f;
#pragma unroll
    for (int k = 0; k < 128; k++) acc += Hs[rl][k] * Ws[k][c];
    if (node < N_NODES) h2h[(size_t)node * 32 + c] = __float2half(acc);
    float sv = acc * as2[c];
    float dv = acc * ad2[c];
#pragma unroll
    for (int msk = 16; msk >= 1; msk >>= 1) {
        sv += __shfl_xor(sv, msk);
        dv += __shfl_xor(dv, msk);
    }
    if (c == 0 && node < N_NODES) {
        asc2[node] = sv;
        adc2[node] = dv;
    }
}

// per-CSR-position layer-2 logits
__global__ void e2_kernel(const int* __restrict__ csr, const int* __restrict__ dpos,
                          const float* __restrict__ asc2, const float* __restrict__ adc2,
                          float* __restrict__ e2) {
    int i = blockIdx.x * blockDim.x + threadIdx.x;
    if (i >= ET) return;
    e2[i] = lrelu(asc2[csr[i]] + adc2[dpos[i]]);
}

// ---------------- Layer-2 aggregation + log_softmax (wave per dst node) ----------------
__global__ __launch_bounds__(256) void agg2_kernel(const __half* __restrict__ h2h,
                                                   const float* __restrict__ e2,
                                                   const float* __restrict__ b2,
                                                   const int* __restrict__ off,
                                                   const int* __restrict__ csr,
                                                   float* __restrict__ out) {
    int wid = threadIdx.x >> 6, lane = threadIdx.x & 63;
    int node = blockIdx.x * 4 + wid;
    if (node >= N_NODES) return;
    int g = lane >> 4;       // edge group 0..3
    int li = lane & 15;      // half2 word index -> channels 2li, 2li+1
    const __half2* h2h2 = (const __half2*)h2h;
    int s0 = off[node], s1 = off[node + 1];
    float m = -1e30f;
    for (int j = s0 + g; j < s1; j += 4) m = fmaxf(m, e2[j]);
    m = fmaxf(m, __shfl_xor(m, 16));
    m = fmaxf(m, __shfl_xor(m, 32));
    float den = 0.f, a0 = 0.f, a1 = 0.f;
    int j = s0 + g;
    for (; j + 8 <= s1; j += 8) {
        int sA = csr[j], sB = csr[j + 4];
        float pA = __expf(e2[j] - m), pB = __expf(e2[j + 4] - m);
        float2 fA = __half22float2(h2h2[(size_t)sA * 16 + li]);
        float2 fB = __half22float2(h2h2[(size_t)sB * 16 + li]);
        den += pA + pB;
        a0 += pA * fA.x + pB * fB.x;
        a1 += pA * fA.y + pB * fB.y;
    }
    for (; j < s1; j += 4) {
        int s = csr[j];
        float p = __expf(e2[j] - m);
        float2 f = __half22float2(h2h2[(size_t)s * 16 + li]);
        den += p;
        a0 += p * f.x;
        a1 += p * f.y;
    }
    den += __shfl_xor(den, 16);
    den += __shfl_xor(den, 32);
    a0 += __shfl_xor(a0, 16);
    a0 += __shfl_xor(a0, 32);
    a1 += __shfl_xor(a1, 16);
    a1 += __shfl_xor(a1, 32);
    float inv = 1.f / (den + 1e-16f);
    float v0 = a0 * inv + b2[2 * li];
    float v1 = a1 * inv + b2[2 * li + 1];
    float mx = fmaxf(v0, v1);
#pragma unroll
    for (int msk = 8; msk >= 1; msk >>= 1) mx = fmaxf(mx, __shfl_xor(mx, msk));
    float se = __expf(v0 - mx) + __expf(v1 - mx);
#pragma unroll
    for (int msk = 8; msk >= 1; msk >>= 1) se += __shfl_xor(se, msk);
    float lse = mx + __logf(se);
    if (lane < 16) {
        ((float2*)out)[(size_t)node * 16 + li] = make_float2(v0 - lse, v1 - lse);
    }
}

extern "C" void kernel_launch(void* const* d_in, const int* in_sizes, int n_in,
                              void* d_out, int out_size, void* d_ws, size_t ws_size,
                              hipStream_t stream) {
    const float* x  = (const float*)d_in[0];
    const int* ei   = (const int*)d_in[1];
    const float* W1 = (const float*)d_in[2];
    const float* as1 = (const float*)d_in[3];
    const float* ad1 = (const float*)d_in[4];
    const float* b1 = (const float*)d_in[5];
    const float* W2 = (const float*)d_in[6];
    const float* as2 = (const float*)d_in[7];
    const float* ad2 = (const float*)d_in[8];
    const float* b2 = (const float*)d_in[9];
    float* out = (float*)d_out;

    char* base = (char*)d_ws;
    __half* h1h = (__half*)base;                       // 12,800,000 B
    float* h1b  = (float*)(base + 12800000);           // 25,600,000 B
    __half* h2h = (__half*)(base + 38400000);          //  3,200,000 B
    float* asc1 = (float*)(base + 41600000);           //    800,000 B
    float* adc1 = (float*)(base + 42400000);           //    800,000 B
    float* asc2 = (float*)(base + 43200000);           //    200,000 B
    float* adc2 = (float*)(base + 43400000);           //    200,000 B
    float* e1   = (float*)(base + 43600000);           // 13,600,000 B
    float* e2   = (float*)(base + 57200000);           //  3,400,000 B
    int* deg    = (int*)(base + 60600000);             //    200,000 B
    int* off    = (int*)(base + 60800000);             //    200,004 B
    int* cursor = (int*)(base + 61000004);             //    200,004 B
    int* csr    = (int*)(base + 61200008);             //  3,400,000 B
    int* dpos   = (int*)(base + 64600008);             //  3,400,000 B

    hipMemsetAsync(deg, 0, N_NODES * sizeof(int), stream);

    gemm1_kernel<<<(N_NODES + 63) / 64, 256, 0, stream>>>(x, W1, h1h);
    ascadc1_kernel<<<(N_NODES + 3) / 4, 256, 0, stream>>>(h1h, as1, ad1, asc1, adc1);
    hist_kernel<<<(E_EDGES + 255) / 256, 256, 0, stream>>>(ei, deg);
    scan_kernel<<<1, 1024, 0, stream>>>(deg, off, cursor);
    fill_kernel<<<(ET + 255) / 256, 256, 0, stream>>>(ei, cursor, asc1, adc1, csr, dpos, e1);
    agg1_kernel<<<(N_NODES + 3) / 4, 256, 0, stream>>>(h1h, e1, b1, off, csr, h1b);
    gemm2_kernel<<<(N_NODES + 7) / 8, 256, 0, stream>>>(h1b, W2, as2, ad2, h2h, asc2, adc2);
    e2_kernel<<<(ET + 255) / 256, 256, 0, stream>>>(csr, dpos, asc2, adc2, e2);
    agg2_kernel<<<(N_NODES + 3) / 4, 256, 0, stream>>>(h2h, e2, b2, off, csr, out);
}

// Round 3
// 326.800 us; speedup vs baseline: 1.9518x; 1.3898x over previous
//
#include <hip/hip_runtime.h>
#include <hip/hip_fp16.h>

#define N_NODES 50000
#define E_EDGES 800000
#define ET (E_EDGES + N_NODES)

typedef _Float16 h8 __attribute__((ext_vector_type(8)));
typedef float f32x16 __attribute__((ext_vector_type(16)));

__device__ __forceinline__ float lrelu(float v) { return v > 0.f ? v : 0.2f * v; }

// ---------- prep: x->fp16, W1->fp16, W2->fp16, zero-pad, degree histogram ----------
__global__ __launch_bounds__(256) void prep_kernel(const float* __restrict__ x,
                                                   const int* __restrict__ ei,
                                                   const float* __restrict__ W1,
                                                   const float* __restrict__ W2,
                                                   _Float16* __restrict__ xh,
                                                   _Float16* __restrict__ w1h,
                                                   _Float16* __restrict__ w2h,
                                                   int* __restrict__ deg) {
    int i = blockIdx.x * 256 + threadIdx.x;
    if (i < 1600000) {
        const float4* x4 = (const float4*)x;
        float4 a = x4[(size_t)i * 2], b = x4[(size_t)i * 2 + 1];
        h8 v;
        v[0] = (_Float16)a.x; v[1] = (_Float16)a.y; v[2] = (_Float16)a.z; v[3] = (_Float16)a.w;
        v[4] = (_Float16)b.x; v[5] = (_Float16)b.y; v[6] = (_Float16)b.z; v[7] = (_Float16)b.w;
        *(h8*)(xh + (size_t)i * 8) = v;
    } else if (i < 2400000) {
        atomicAdd(&deg[ei[E_EDGES + (i - 1600000)]], 1);
    } else if (i < 2404096) {
        int j = (i - 2400000) * 8;
#pragma unroll
        for (int t = 0; t < 8; t++) w1h[j + t] = (_Float16)W1[j + t];
    } else if (i < 2404608) {
        int j = (i - 2404096) * 8;
#pragma unroll
        for (int t = 0; t < 8; t++) w2h[j + t] = (_Float16)W2[j + t];
    } else if (i < 2405376) {
        int j = (i - 2404608) * 8;
#pragma unroll
        for (int t = 0; t < 8; t++) w1h[136 * 256 + j + t] = (_Float16)0.f;
    }
}

// ---------- Aw: rows 128..135 of w1h = attention-combined weights ----------
// Aw[h][k] = sum_c a1[h][c] * W1[h*32+c][k]  (h<4: a_src1, h>=4: a_dst1)
__global__ __launch_bounds__(256) void aw_kernel(const float* __restrict__ W1,
                                                 const float* __restrict__ as1,
                                                 const float* __restrict__ ad1,
                                                 _Float16* __restrict__ w1h) {
    int i = blockIdx.x * 256 + threadIdx.x;  // 0..2047
    int h = i >> 8, k = i & 255;
    const float* av = (h < 4 ? as1 : ad1) + (h & 3) * 32;
    const float* wb = W1 + (size_t)(h & 3) * 32 * 256 + k;
    float s = 0.f;
#pragma unroll
    for (int c = 0; c < 32; c++) s += av[c] * wb[(size_t)c * 256];
    w1h[(size_t)(128 + h) * 256 + k] = (_Float16)s;
}

// ---------- GEMM1 (MFMA): h1h[N,128] = xh[N,256] @ w1h[0:128]^T ; cols 128..135 -> asc1/adc1 ----------
__global__ __launch_bounds__(256) void gemm1_mfma(const _Float16* __restrict__ xh,
                                                  const _Float16* __restrict__ w1h,
                                                  _Float16* __restrict__ h1h,
                                                  float* __restrict__ asc1,
                                                  float* __restrict__ adc1) {
    int wid = threadIdx.x >> 6, lane = threadIdx.x & 63;
    int rbase = blockIdx.x * 128 + wid * 32;
    if (rbase >= N_NODES) return;
    int l31 = lane & 31, l5 = lane >> 5;
    int ar = rbase + l31;
    if (ar > N_NODES - 1) ar = N_NODES - 1;
    const _Float16* ap = xh + (size_t)ar * 256 + l5 * 8;
    const _Float16* bp = w1h + (size_t)l31 * 256 + l5 * 8;
    f32x16 acc0 = {}, acc1 = {}, acc2 = {}, acc3 = {}, acc4 = {};
#pragma unroll 4
    for (int ks = 0; ks < 16; ks++) {
        h8 av = *(const h8*)(ap + ks * 16);
        h8 b0 = *(const h8*)(bp + ks * 16);
        h8 b1 = *(const h8*)(bp + 32 * 256 + ks * 16);
        h8 b2 = *(const h8*)(bp + 64 * 256 + ks * 16);
        h8 b3 = *(const h8*)(bp + 96 * 256 + ks * 16);
        h8 b4 = *(const h8*)(bp + 128 * 256 + ks * 16);
        acc0 = __builtin_amdgcn_mfma_f32_32x32x16_f16(av, b0, acc0, 0, 0, 0);
        acc1 = __builtin_amdgcn_mfma_f32_32x32x16_f16(av, b1, acc1, 0, 0, 0);
        acc2 = __builtin_amdgcn_mfma_f32_32x32x16_f16(av, b2, acc2, 0, 0, 0);
        acc3 = __builtin_amdgcn_mfma_f32_32x32x16_f16(av, b3, acc3, 0, 0, 0);
        acc4 = __builtin_amdgcn_mfma_f32_32x32x16_f16(av, b4, acc4, 0, 0, 0);
    }
#pragma unroll
    for (int j = 0; j < 16; j++) {
        int row = rbase + (j & 3) + 8 * (j >> 2) + 4 * l5;
        if (row < N_NODES) {
            h1h[(size_t)row * 128 + 0  + l31] = (_Float16)acc0[j];
            h1h[(size_t)row * 128 + 32 + l31] = (_Float16)acc1[j];
            h1h[(size_t)row * 128 + 64 + l31] = (_Float16)acc2[j];
            h1h[(size_t)row * 128 + 96 + l31] = (_Float16)acc3[j];
            float v4 = acc4[j];
            if (l31 < 4) asc1[(size_t)row * 4 + l31] = v4;
            else if (l31 < 8) adc1[(size_t)row * 4 + (l31 - 4)] = v4;
        }
    }
}

// ---------- CSR scan ----------
__global__ __launch_bounds__(1024) void scan_kernel(const int* __restrict__ deg,
                                                    int* __restrict__ off,
                                                    int* __restrict__ cursor) {
    __shared__ int sums[1024];
    int t = threadIdx.x;
    const int chunk = 49;
    int s0 = t * chunk, s1 = s0 + chunk;
    if (s1 > N_NODES) s1 = N_NODES;
    if (s0 > N_NODES) s0 = N_NODES;
    int local = 0;
    for (int n = s0; n < s1; n++) local += deg[n] + 1;
    sums[t] = local;
    __syncthreads();
    for (int d = 1; d < 1024; d <<= 1) {
        int v = (t >= d) ? sums[t - d] : 0;
        __syncthreads();
        sums[t] += v;
        __syncthreads();
    }
    int run = sums[t] - local;
    for (int n = s0; n < s1; n++) {
        off[n] = run;
        cursor[n] = run;
        run += deg[n] + 1;
    }
    if (t == 1023) off[N_NODES] = run;
}

// ---------- fill CSR + per-edge p1 = exp(lrelu(asc+adc)) (fp16, CSR order) ----------
__global__ void fill_kernel(const int* __restrict__ ei, int* __restrict__ cursor,
                            const float* __restrict__ asc1, const float* __restrict__ adc1,
                            int* __restrict__ csr, int* __restrict__ dpos,
                            __half* __restrict__ e1p) {
    int i = blockIdx.x * blockDim.x + threadIdx.x;
    if (i >= ET) return;
    int s, d;
    if (i < E_EDGES) { s = ei[i]; d = ei[E_EDGES + i]; }
    else { s = i - E_EDGES; d = s; }
    int pos = atomicAdd(&cursor[d], 1);
    csr[pos] = s;
    dpos[pos] = d;
    float4 av = *(const float4*)(asc1 + (size_t)s * 4);
    float4 dv = *(const float4*)(adc1 + (size_t)d * 4);
    float p0 = __expf(lrelu(av.x + dv.x));
    float p1 = __expf(lrelu(av.y + dv.y));
    float p2 = __expf(lrelu(av.z + dv.z));
    float p3 = __expf(lrelu(av.w + dv.w));
    __half2* e2h = (__half2*)e1p;
    e2h[(size_t)pos * 2]     = __floats2half2_rn(p0, p1);
    e2h[(size_t)pos * 2 + 1] = __floats2half2_rn(p2, p3);
}

// ---------- Layer-1 aggregation (wave per dst node, single pass, no exp) ----------
__global__ __launch_bounds__(256) void agg1_kernel(const __half* __restrict__ h1h,
                                                   const __half* __restrict__ e1p,
                                                   const float* __restrict__ b1,
                                                   const int* __restrict__ off,
                                                   const int* __restrict__ csr,
                                                   __half* __restrict__ h1b) {
    int wid = threadIdx.x >> 6, lane = threadIdx.x & 63;
    int node = blockIdx.x * 4 + wid;
    if (node >= N_NODES) return;
    int hh = lane >> 4;
    const __half2* h1h2 = (const __half2*)h1h;
    int s0 = off[node], s1 = off[node + 1];
    float den = 0.f, a0 = 0.f, a1 = 0.f;
    int j = s0;
    for (; j + 4 <= s1; j += 4) {
        int sA = csr[j], sB = csr[j + 1], sC = csr[j + 2], sD = csr[j + 3];
        float pA = __half2float(e1p[(size_t)(j + 0) * 4 + hh]);
        float pB = __half2float(e1p[(size_t)(j + 1) * 4 + hh]);
        float pC = __half2float(e1p[(size_t)(j + 2) * 4 + hh]);
        float pD = __half2float(e1p[(size_t)(j + 3) * 4 + hh]);
        __half2 hA = h1h2[(size_t)sA * 64 + lane];
        __half2 hB = h1h2[(size_t)sB * 64 + lane];
        __half2 hC = h1h2[(size_t)sC * 64 + lane];
        __half2 hD = h1h2[(size_t)sD * 64 + lane];
        den += (pA + pB) + (pC + pD);
        float2 fA = __half22float2(hA), fB = __half22float2(hB);
        float2 fC = __half22float2(hC), fD = __half22float2(hD);
        a0 += pA * fA.x + pB * fB.x + pC * fC.x + pD * fD.x;
        a1 += pA * fA.y + pB * fB.y + pC * fC.y + pD * fD.y;
    }
    for (; j < s1; j++) {
        int s = csr[j];
        float p = __half2float(e1p[(size_t)j * 4 + hh]);
        float2 f = __half22float2(h1h2[(size_t)s * 64 + lane]);
        den += p;
        a0 += p * f.x;
        a1 += p * f.y;
    }
    float inv = 1.f / (den + 1e-16f);
    float o0 = fmaxf(a0 * inv + b1[2 * lane], 0.f);
    float o1 = fmaxf(a1 * inv + b1[2 * lane + 1], 0.f);
    ((__half2*)h1b)[(size_t)node * 64 + lane] = __floats2half2_rn(o0, o1);
}

// ---------- GEMM2 (MFMA): h2h[N,32] = h1b @ w2h^T ; epilogue asc2/adc2 ----------
__global__ __launch_bounds__(256) void gemm2_mfma(const __half* __restrict__ h1b,
                                                  const _Float16* __restrict__ w2h,
                                                  const float* __restrict__ as2,
                                                  const float* __restrict__ ad2,
                                                  __half* __restrict__ h2h,
                                                  float* __restrict__ asc2,
                                                  float* __restrict__ adc2) {
    int wid = threadIdx.x >> 6, lane = threadIdx.x & 63;
    int rbase = blockIdx.x * 128 + wid * 32;
    if (rbase >= N_NODES) return;
    int l31 = lane & 31, l5 = lane >> 5;
    int ar = rbase + l31;
    if (ar > N_NODES - 1) ar = N_NODES - 1;
    const _Float16* ap = (const _Float16*)h1b + (size_t)ar * 128 + l5 * 8;
    const _Float16* bp = w2h + (size_t)l31 * 128 + l5 * 8;
    f32x16 acc = {};
#pragma unroll
    for (int ks = 0; ks < 8; ks++) {
        h8 av = *(const h8*)(ap + ks * 16);
        h8 bv = *(const h8*)(bp + ks * 16);
        acc = __builtin_amdgcn_mfma_f32_32x32x16_f16(av, bv, acc, 0, 0, 0);
    }
    float asw = as2[l31], adw = ad2[l31];
#pragma unroll
    for (int j = 0; j < 16; j++) {
        int row = rbase + (j & 3) + 8 * (j >> 2) + 4 * l5;
        float v = acc[j];
        float sv = v * asw, dv = v * adw;
#pragma unroll
        for (int m = 1; m <= 16; m <<= 1) {
            sv += __shfl_xor(sv, m);
            dv += __shfl_xor(dv, m);
        }
        if (row < N_NODES) {
            h2h[(size_t)row * 32 + l31] = __float2half(v);
            if (l31 == 0) { asc2[row] = sv; adc2[row] = dv; }
        }
    }
}

// ---------- per-CSR-position p2 = exp(lrelu(asc2+adc2)) ----------
__global__ void e2_kernel(const int* __restrict__ csr, const int* __restrict__ dpos,
                          const float* __restrict__ asc2, const float* __restrict__ adc2,
                          float* __restrict__ e2) {
    int i = blockIdx.x * blockDim.x + threadIdx.x;
    if (i >= ET) return;
    e2[i] = __expf(lrelu(asc2[csr[i]] + adc2[dpos[i]]));
}

// ---------- Layer-2 aggregation + log_softmax ----------
__global__ __launch_bounds__(256) void agg2_kernel(const __half* __restrict__ h2h,
                                                   const float* __restrict__ e2,
                                                   const float* __restrict__ b2,
                                                   const int* __restrict__ off,
                                                   const int* __restrict__ csr,
                                                   float* __restrict__ out) {
    int wid = threadIdx.x >> 6, lane = threadIdx.x & 63;
    int node = blockIdx.x * 4 + wid;
    if (node >= N_NODES) return;
    int g = lane >> 4;
    int li = lane & 15;
    const __half2* h2h2 = (const __half2*)h2h;
    int s0 = off[node], s1 = off[node + 1];
    float den = 0.f, a0 = 0.f, a1 = 0.f;
    int j = s0 + g;
    for (; j + 8 <= s1; j += 8) {
        int sA = csr[j], sB = csr[j + 4];
        float pA = e2[j], pB = e2[j + 4];
        float2 fA = __half22float2(h2h2[(size_t)sA * 16 + li]);
        float2 fB = __half22float2(h2h2[(size_t)sB * 16 + li]);
        den += pA + pB;
        a0 += pA * fA.x + pB * fB.x;
        a1 += pA * fA.y + pB * fB.y;
    }
    for (; j < s1; j += 4) {
        int s = csr[j];
        float p = e2[j];
        float2 f = __half22float2(h2h2[(size_t)s * 16 + li]);
        den += p;
        a0 += p * f.x;
        a1 += p * f.y;
    }
    den += __shfl_xor(den, 16); den += __shfl_xor(den, 32);
    a0 += __shfl_xor(a0, 16);  a0 += __shfl_xor(a0, 32);
    a1 += __shfl_xor(a1, 16);  a1 += __shfl_xor(a1, 32);
    float inv = 1.f / (den + 1e-16f);
    float v0 = a0 * inv + b2[2 * li];
    float v1 = a1 * inv + b2[2 * li + 1];
    float mx = fmaxf(v0, v1);
#pragma unroll
    for (int msk = 8; msk >= 1; msk >>= 1) mx = fmaxf(mx, __shfl_xor(mx, msk));
    float se = __expf(v0 - mx) + __expf(v1 - mx);
#pragma unroll
    for (int msk = 8; msk >= 1; msk >>= 1) se += __shfl_xor(se, msk);
    float lse = mx + __logf(se);
    if (lane < 16) {
        ((float2*)out)[(size_t)node * 16 + li] = make_float2(v0 - lse, v1 - lse);
    }
}

extern "C" void kernel_launch(void* const* d_in, const int* in_sizes, int n_in,
                              void* d_out, int out_size, void* d_ws, size_t ws_size,
                              hipStream_t stream) {
    const float* x   = (const float*)d_in[0];
    const int* ei    = (const int*)d_in[1];
    const float* W1  = (const float*)d_in[2];
    const float* as1 = (const float*)d_in[3];
    const float* ad1 = (const float*)d_in[4];
    const float* b1  = (const float*)d_in[5];
    const float* W2  = (const float*)d_in[6];
    const float* as2 = (const float*)d_in[7];
    const float* ad2 = (const float*)d_in[8];
    const float* b2  = (const float*)d_in[9];
    float* out = (float*)d_out;

    char* base = (char*)d_ws;
    // Region X (25,600,000 B): xh during prep/gemm1; then e1p/e2/dpos
    _Float16* xh = (_Float16*)base;
    __half* e1p  = (__half*)base;                      // ET*8   = 6,800,000
    float* e2    = (float*)(base + 6800000);           // ET*4   = 3,400,000
    int* dpos    = (int*)(base + 10200000);            // ET*4   = 3,400,000
    _Float16* w1h = (_Float16*)(base + 25600000);      // 160*256*2 = 81,920
    _Float16* w2h = (_Float16*)(base + 25681920);      // 4096*2 = 8,192
    _Float16* h1h = (_Float16*)(base + 25690112);      // 12,800,000
    __half* h1b   = (__half*)(base + 38490112);        // 12,800,000
    __half* h2h   = (__half*)(base + 51290112);        //  3,200,000
    float* asc1   = (float*)(base + 54490112);         //    800,000
    float* adc1   = (float*)(base + 55290112);         //    800,000
    float* asc2   = (float*)(base + 56090112);         //    200,000
    float* adc2   = (float*)(base + 56290112);         //    200,000
    int* deg      = (int*)(base + 56490112);           //    200,000
    int* off      = (int*)(base + 56690112);           //    200,004
    int* cursor   = (int*)(base + 56890116);           //    200,004
    int* csr      = (int*)(base + 57090120);           //  3,400,000

    hipMemsetAsync(deg, 0, N_NODES * sizeof(int), stream);

    prep_kernel<<<(2405376 + 255) / 256, 256, 0, stream>>>(x, ei, W1, W2, xh, w1h, w2h, deg);
    aw_kernel<<<8, 256, 0, stream>>>(W1, as1, ad1, w1h);
    gemm1_mfma<<<391, 256, 0, stream>>>(xh, w1h, h1h, asc1, adc1);
    scan_kernel<<<1, 1024, 0, stream>>>(deg, off, cursor);
    fill_kernel<<<(ET + 255) / 256, 256, 0, stream>>>(ei, cursor, asc1, adc1, csr, dpos, e1p);
    agg1_kernel<<<(N_NODES + 3) / 4, 256, 0, stream>>>((const __half*)h1h, e1p, b1, off, csr, h1b);
    gemm2_mfma<<<391, 256, 0, stream>>>(h1b, w2h, as2, ad2, h2h, asc2, adc2);
    e2_kernel<<<(ET + 255) / 256, 256, 0, stream>>>(csr, dpos, asc2, adc2, e2);
    agg2_kernel<<<(N_NODES + 3) / 4, 256, 0, stream>>>(h2h, e2, b2, off, csr, out);
}

// Round 4
// 226.837 us; speedup vs baseline: 2.8120x; 1.4407x over previous
//
#include <hip/hip_runtime.h>
#include <hip/hip_fp16.h>

#define N_NODES 50000
#define E_EDGES 800000
#define ET (E_EDGES + N_NODES)

typedef _Float16 h8 __attribute__((ext_vector_type(8)));
typedef float f32x16 __attribute__((ext_vector_type(16)));

__device__ __forceinline__ float lrelu(float v) { return v > 0.f ? v : 0.2f * v; }

// ---------- prep: x->fp16, W1->fp16, W2->fp16, zero-pad, degree histogram ----------
__global__ __launch_bounds__(256) void prep_kernel(const float* __restrict__ x,
                                                   const int* __restrict__ ei,
                                                   const float* __restrict__ W1,
                                                   const float* __restrict__ W2,
                                                   _Float16* __restrict__ xh,
                                                   _Float16* __restrict__ w1h,
                                                   _Float16* __restrict__ w2h,
                                                   int* __restrict__ deg) {
    int i = blockIdx.x * 256 + threadIdx.x;
    if (i < 1600000) {
        const float4* x4 = (const float4*)x;
        float4 a = x4[(size_t)i * 2], b = x4[(size_t)i * 2 + 1];
        h8 v;
        v[0] = (_Float16)a.x; v[1] = (_Float16)a.y; v[2] = (_Float16)a.z; v[3] = (_Float16)a.w;
        v[4] = (_Float16)b.x; v[5] = (_Float16)b.y; v[6] = (_Float16)b.z; v[7] = (_Float16)b.w;
        *(h8*)(xh + (size_t)i * 8) = v;
    } else if (i < 2400000) {
        atomicAdd(&deg[ei[E_EDGES + (i - 1600000)]], 1);
    } else if (i < 2404096) {
        int j = (i - 2400000) * 8;
#pragma unroll
        for (int t = 0; t < 8; t++) w1h[j + t] = (_Float16)W1[j + t];
    } else if (i < 2404608) {
        int j = (i - 2404096) * 8;
#pragma unroll
        for (int t = 0; t < 8; t++) w2h[j + t] = (_Float16)W2[j + t];
    } else if (i < 2405376) {
        int j = (i - 2404608) * 8;
#pragma unroll
        for (int t = 0; t < 8; t++) w1h[136 * 256 + j + t] = (_Float16)0.f;
    }
}

// ---------- Aw: rows 128..135 of w1h = attention-combined weights ----------
__global__ __launch_bounds__(256) void aw_kernel(const float* __restrict__ W1,
                                                 const float* __restrict__ as1,
                                                 const float* __restrict__ ad1,
                                                 _Float16* __restrict__ w1h) {
    int i = blockIdx.x * 256 + threadIdx.x;  // 0..2047
    int h = i >> 8, k = i & 255;
    const float* av = (h < 4 ? as1 : ad1) + (h & 3) * 32;
    const float* wb = W1 + (size_t)(h & 3) * 32 * 256 + k;
    float s = 0.f;
#pragma unroll
    for (int c = 0; c < 32; c++) s += av[c] * wb[(size_t)c * 256];
    w1h[(size_t)(128 + h) * 256 + k] = (_Float16)s;
}

// ---------- GEMM1 (MFMA): h1h[N,128] = xh[N,256] @ w1h[0:128]^T ; cols 128..135 -> asc1/adc1 ----------
__global__ __launch_bounds__(256) void gemm1_mfma(const _Float16* __restrict__ xh,
                                                  const _Float16* __restrict__ w1h,
                                                  _Float16* __restrict__ h1h,
                                                  float* __restrict__ asc1,
                                                  float* __restrict__ adc1) {
    int wid = threadIdx.x >> 6, lane = threadIdx.x & 63;
    int rbase = blockIdx.x * 128 + wid * 32;
    if (rbase >= N_NODES) return;
    int l31 = lane & 31, l5 = lane >> 5;
    int ar = rbase + l31;
    if (ar > N_NODES - 1) ar = N_NODES - 1;
    const _Float16* ap = xh + (size_t)ar * 256 + l5 * 8;
    const _Float16* bp = w1h + (size_t)l31 * 256 + l5 * 8;
    f32x16 acc0 = {}, acc1 = {}, acc2 = {}, acc3 = {}, acc4 = {};
#pragma unroll 4
    for (int ks = 0; ks < 16; ks++) {
        h8 av = *(const h8*)(ap + ks * 16);
        h8 b0 = *(const h8*)(bp + ks * 16);
        h8 b1 = *(const h8*)(bp + 32 * 256 + ks * 16);
        h8 b2 = *(const h8*)(bp + 64 * 256 + ks * 16);
        h8 b3 = *(const h8*)(bp + 96 * 256 + ks * 16);
        h8 b4 = *(const h8*)(bp + 128 * 256 + ks * 16);
        acc0 = __builtin_amdgcn_mfma_f32_32x32x16_f16(av, b0, acc0, 0, 0, 0);
        acc1 = __builtin_amdgcn_mfma_f32_32x32x16_f16(av, b1, acc1, 0, 0, 0);
        acc2 = __builtin_amdgcn_mfma_f32_32x32x16_f16(av, b2, acc2, 0, 0, 0);
        acc3 = __builtin_amdgcn_mfma_f32_32x32x16_f16(av, b3, acc3, 0, 0, 0);
        acc4 = __builtin_amdgcn_mfma_f32_32x32x16_f16(av, b4, acc4, 0, 0, 0);
    }
#pragma unroll
    for (int j = 0; j < 16; j++) {
        int row = rbase + (j & 3) + 8 * (j >> 2) + 4 * l5;
        if (row < N_NODES) {
            h1h[(size_t)row * 128 + 0  + l31] = (_Float16)acc0[j];
            h1h[(size_t)row * 128 + 32 + l31] = (_Float16)acc1[j];
            h1h[(size_t)row * 128 + 64 + l31] = (_Float16)acc2[j];
            h1h[(size_t)row * 128 + 96 + l31] = (_Float16)acc3[j];
            float v4 = acc4[j];
            if (l31 < 4) asc1[(size_t)row * 4 + l31] = v4;
            else if (l31 < 8) adc1[(size_t)row * 4 + (l31 - 4)] = v4;
        }
    }
}

// ---------- device-wide scan of (deg+1), 3 stages ----------
__global__ __launch_bounds__(1024) void scanA_kernel(const int* __restrict__ deg,
                                                     int* __restrict__ off,
                                                     int* __restrict__ bsum) {
    __shared__ int s[1024];
    int t = threadIdx.x;
    int n = blockIdx.x * 1024 + t;
    int v = (n < N_NODES) ? deg[n] + 1 : 0;
    s[t] = v;
    __syncthreads();
    for (int d = 1; d < 1024; d <<= 1) {
        int u = (t >= d) ? s[t - d] : 0;
        __syncthreads();
        s[t] += u;
        __syncthreads();
    }
    if (n < N_NODES) off[n] = s[t] - v;  // block-local exclusive prefix
    if (t == 1023) bsum[blockIdx.x] = s[1023];
}

__global__ void scanB_kernel(int* __restrict__ bsum) {
    int t = threadIdx.x;  // 64 threads, 1 wave
    int v = (t < 49) ? bsum[t] : 0;
#pragma unroll
    for (int d = 1; d < 64; d <<= 1) {
        int u = __shfl_up(v, d);
        if (t >= d) v += u;
    }
    if (t < 49) bsum[t] = v;  // inclusive block sums
}

__global__ __launch_bounds__(1024) void scanC_kernel(const int* __restrict__ bsum,
                                                     int* __restrict__ off,
                                                     int* __restrict__ cursor) {
    int b = blockIdx.x;
    int base = (b == 0) ? 0 : bsum[b - 1];
    int n = b * 1024 + threadIdx.x;
    if (n < N_NODES) {
        int o = off[n] + base;
        off[n] = o;
        cursor[n] = o;
    }
    if (n == 0) off[N_NODES] = ET;
}

// ---------- fill CSR + per-edge p1 = exp(lrelu(asc+adc)) (fp16, CSR order) ----------
__global__ void fill_kernel(const int* __restrict__ ei, int* __restrict__ cursor,
                            const float* __restrict__ asc1, const float* __restrict__ adc1,
                            int* __restrict__ csr, int* __restrict__ dpos,
                            __half* __restrict__ e1p) {
    int i = blockIdx.x * blockDim.x + threadIdx.x;
    if (i >= ET) return;
    int s, d;
    if (i < E_EDGES) { s = ei[i]; d = ei[E_EDGES + i]; }
    else { s = i - E_EDGES; d = s; }
    int pos = atomicAdd(&cursor[d], 1);
    csr[pos] = s;
    dpos[pos] = d;
    float4 av = *(const float4*)(asc1 + (size_t)s * 4);
    float4 dv = *(const float4*)(adc1 + (size_t)d * 4);
    float p0 = __expf(lrelu(av.x + dv.x));
    float p1 = __expf(lrelu(av.y + dv.y));
    float p2 = __expf(lrelu(av.z + dv.z));
    float p3 = __expf(lrelu(av.w + dv.w));
    __half2* e2h = (__half2*)e1p;
    e2h[(size_t)pos * 2]     = __floats2half2_rn(p0, p1);
    e2h[(size_t)pos * 2 + 1] = __floats2half2_rn(p2, p3);
}

// ---------- Layer-1 aggregation (wave per dst node, single pass, no exp) ----------
__global__ __launch_bounds__(256) void agg1_kernel(const __half* __restrict__ h1h,
                                                   const __half* __restrict__ e1p,
                                                   const float* __restrict__ b1,
                                                   const int* __restrict__ off,
                                                   const int* __restrict__ csr,
                                                   __half* __restrict__ h1b) {
    int wid = threadIdx.x >> 6, lane = threadIdx.x & 63;
    int node = blockIdx.x * 4 + wid;
    if (node >= N_NODES) return;
    int hh = lane >> 4;
    const __half2* h1h2 = (const __half2*)h1h;
    int s0 = off[node], s1 = off[node + 1];
    float den = 0.f, a0 = 0.f, a1 = 0.f;
    int j = s0;
    for (; j + 4 <= s1; j += 4) {
        int sA = csr[j], sB = csr[j + 1], sC = csr[j + 2], sD = csr[j + 3];
        float pA = __half2float(e1p[(size_t)(j + 0) * 4 + hh]);
        float pB = __half2float(e1p[(size_t)(j + 1) * 4 + hh]);
        float pC = __half2float(e1p[(size_t)(j + 2) * 4 + hh]);
        float pD = __half2float(e1p[(size_t)(j + 3) * 4 + hh]);
        __half2 hA = h1h2[(size_t)sA * 64 + lane];
        __half2 hB = h1h2[(size_t)sB * 64 + lane];
        __half2 hC = h1h2[(size_t)sC * 64 + lane];
        __half2 hD = h1h2[(size_t)sD * 64 + lane];
        den += (pA + pB) + (pC + pD);
        float2 fA = __half22float2(hA), fB = __half22float2(hB);
        float2 fC = __half22float2(hC), fD = __half22float2(hD);
        a0 += pA * fA.x + pB * fB.x + pC * fC.x + pD * fD.x;
        a1 += pA * fA.y + pB * fB.y + pC * fC.y + pD * fD.y;
    }
    for (; j < s1; j++) {
        int s = csr[j];
        float p = __half2float(e1p[(size_t)j * 4 + hh]);
        float2 f = __half22float2(h1h2[(size_t)s * 64 + lane]);
        den += p;
        a0 += p * f.x;
        a1 += p * f.y;
    }
    float inv = 1.f / (den + 1e-16f);
    float o0 = fmaxf(a0 * inv + b1[2 * lane], 0.f);
    float o1 = fmaxf(a1 * inv + b1[2 * lane + 1], 0.f);
    ((__half2*)h1b)[(size_t)node * 64 + lane] = __floats2half2_rn(o0, o1);
}

// ---------- GEMM2 (MFMA): h2h[N,32] = h1b @ w2h^T ; epilogue asc2/adc2 ----------
__global__ __launch_bounds__(256) void gemm2_mfma(const __half* __restrict__ h1b,
                                                  const _Float16* __restrict__ w2h,
                                                  const float* __restrict__ as2,
                                                  const float* __restrict__ ad2,
                                                  __half* __restrict__ h2h,
                                                  float* __restrict__ asc2,
                                                  float* __restrict__ adc2) {
    int wid = threadIdx.x >> 6, lane = threadIdx.x & 63;
    int rbase = blockIdx.x * 128 + wid * 32;
    if (rbase >= N_NODES) return;
    int l31 = lane & 31, l5 = lane >> 5;
    int ar = rbase + l31;
    if (ar > N_NODES - 1) ar = N_NODES - 1;
    const _Float16* ap = (const _Float16*)h1b + (size_t)ar * 128 + l5 * 8;
    const _Float16* bp = w2h + (size_t)l31 * 128 + l5 * 8;
    f32x16 acc = {};
#pragma unroll
    for (int ks = 0; ks < 8; ks++) {
        h8 av = *(const h8*)(ap + ks * 16);
        h8 bv = *(const h8*)(bp + ks * 16);
        acc = __builtin_amdgcn_mfma_f32_32x32x16_f16(av, bv, acc, 0, 0, 0);
    }
    float asw = as2[l31], adw = ad2[l31];
#pragma unroll
    for (int j = 0; j < 16; j++) {
        int row = rbase + (j & 3) + 8 * (j >> 2) + 4 * l5;
        float v = acc[j];
        float sv = v * asw, dv = v * adw;
#pragma unroll
        for (int m = 1; m <= 16; m <<= 1) {
            sv += __shfl_xor(sv, m);
            dv += __shfl_xor(dv, m);
        }
        if (row < N_NODES) {
            h2h[(size_t)row * 32 + l31] = __float2half(v);
            if (l31 == 0) { asc2[row] = sv; adc2[row] = dv; }
        }
    }
}

// ---------- per-CSR-position p2 = exp(lrelu(asc2+adc2)) ----------
__global__ void e2_kernel(const int* __restrict__ csr, const int* __restrict__ dpos,
                          const float* __restrict__ asc2, const float* __restrict__ adc2,
                          float* __restrict__ e2) {
    int i = blockIdx.x * blockDim.x + threadIdx.x;
    if (i >= ET) return;
    e2[i] = __expf(lrelu(asc2[csr[i]] + adc2[dpos[i]]));
}

// ---------- Layer-2 aggregation + log_softmax ----------
__global__ __launch_bounds__(256) void agg2_kernel(const __half* __restrict__ h2h,
                                                   const float* __restrict__ e2,
                                                   const float* __restrict__ b2,
                                                   const int* __restrict__ off,
                                                   const int* __restrict__ csr,
                                                   float* __restrict__ out) {
    int wid = threadIdx.x >> 6, lane = threadIdx.x & 63;
    int node = blockIdx.x * 4 + wid;
    if (node >= N_NODES) return;
    int g = lane >> 4;
    int li = lane & 15;
    const __half2* h2h2 = (const __half2*)h2h;
    int s0 = off[node], s1 = off[node + 1];
    float den = 0.f, a0 = 0.f, a1 = 0.f;
    int j = s0 + g;
    for (; j + 8 <= s1; j += 8) {
        int sA = csr[j], sB = csr[j + 4];
        float pA = e2[j], pB = e2[j + 4];
        float2 fA = __half22float2(h2h2[(size_t)sA * 16 + li]);
        float2 fB = __half22float2(h2h2[(size_t)sB * 16 + li]);
        den += pA + pB;
        a0 += pA * fA.x + pB * fB.x;
        a1 += pA * fA.y + pB * fB.y;
    }
    for (; j < s1; j += 4) {
        int s = csr[j];
        float p = e2[j];
        float2 f = __half22float2(h2h2[(size_t)s * 16 + li]);
        den += p;
        a0 += p * f.x;
        a1 += p * f.y;
    }
    den += __shfl_xor(den, 16); den += __shfl_xor(den, 32);
    a0 += __shfl_xor(a0, 16);  a0 += __shfl_xor(a0, 32);
    a1 += __shfl_xor(a1, 16);  a1 += __shfl_xor(a1, 32);
    float inv = 1.f / (den + 1e-16f);
    float v0 = a0 * inv + b2[2 * li];
    float v1 = a1 * inv + b2[2 * li + 1];
    float mx = fmaxf(v0, v1);
#pragma unroll
    for (int msk = 8; msk >= 1; msk >>= 1) mx = fmaxf(mx, __shfl_xor(mx, msk));
    float se = __expf(v0 - mx) + __expf(v1 - mx);
#pragma unroll
    for (int msk = 8; msk >= 1; msk >>= 1) se += __shfl_xor(se, msk);
    float lse = mx + __logf(se);
    if (lane < 16) {
        ((float2*)out)[(size_t)node * 16 + li] = make_float2(v0 - lse, v1 - lse);
    }
}

extern "C" void kernel_launch(void* const* d_in, const int* in_sizes, int n_in,
                              void* d_out, int out_size, void* d_ws, size_t ws_size,
                              hipStream_t stream) {
    const float* x   = (const float*)d_in[0];
    const int* ei    = (const int*)d_in[1];
    const float* W1  = (const float*)d_in[2];
    const float* as1 = (const float*)d_in[3];
    const float* ad1 = (const float*)d_in[4];
    const float* b1  = (const float*)d_in[5];
    const float* W2  = (const float*)d_in[6];
    const float* as2 = (const float*)d_in[7];
    const float* ad2 = (const float*)d_in[8];
    const float* b2  = (const float*)d_in[9];
    float* out = (float*)d_out;

    char* base = (char*)d_ws;
    // Region X (25,600,000 B): xh during prep/gemm1; then e1p/e2/dpos
    _Float16* xh = (_Float16*)base;
    __half* e1p  = (__half*)base;                      // ET*8   = 6,800,000
    float* e2    = (float*)(base + 6800000);           // ET*4   = 3,400,000
    int* dpos    = (int*)(base + 10200000);            // ET*4   = 3,400,000
    _Float16* w1h = (_Float16*)(base + 25600000);      // 160*256*2 = 81,920
    _Float16* w2h = (_Float16*)(base + 25681920);      // 4096*2 = 8,192
    _Float16* h1h = (_Float16*)(base + 25690112);      // 12,800,000
    __half* h1b   = (__half*)(base + 38490112);        // 12,800,000
    __half* h2h   = (__half*)(base + 51290112);        //  3,200,000
    float* asc1   = (float*)(base + 54490112);         //    800,000
    float* adc1   = (float*)(base + 55290112);         //    800,000
    float* asc2   = (float*)(base + 56090112);         //    200,000
    float* adc2   = (float*)(base + 56290112);         //    200,000
    int* deg      = (int*)(base + 56490112);           //    200,000
    int* off      = (int*)(base + 56690112);           //    200,004
    int* cursor   = (int*)(base + 56890116);           //    200,004
    int* csr      = (int*)(base + 57090120);           //  3,400,000
    int* bsum     = (int*)(base + 60490120);           //        256

    hipMemsetAsync(deg, 0, N_NODES * sizeof(int), stream);

    prep_kernel<<<(2405376 + 255) / 256, 256, 0, stream>>>(x, ei, W1, W2, xh, w1h, w2h, deg);
    aw_kernel<<<8, 256, 0, stream>>>(W1, as1, ad1, w1h);
    gemm1_mfma<<<391, 256, 0, stream>>>(xh, w1h, h1h, asc1, adc1);
    scanA_kernel<<<49, 1024, 0, stream>>>(deg, off, bsum);
    scanB_kernel<<<1, 64, 0, stream>>>(bsum);
    scanC_kernel<<<49, 1024, 0, stream>>>(bsum, off, cursor);
    fill_kernel<<<(ET + 255) / 256, 256, 0, stream>>>(ei, cursor, asc1, adc1, csr, dpos, e1p);
    agg1_kernel<<<(N_NODES + 3) / 4, 256, 0, stream>>>((const __half*)h1h, e1p, b1, off, csr, h1b);
    gemm2_mfma<<<391, 256, 0, stream>>>(h1b, w2h, as2, ad2, h2h, asc2, adc2);
    e2_kernel<<<(ET + 255) / 256, 256, 0, stream>>>(csr, dpos, asc2, adc2, e2);
    agg2_kernel<<<(N_NODES + 3) / 4, 256, 0, stream>>>(h2h, e2, b2, off, csr, out);
}

// Round 5
// 210.112 us; speedup vs baseline: 3.0358x; 1.0796x over previous
//
#include <hip/hip_runtime.h>
#include <hip/hip_fp16.h>

#define N_NODES 50000
#define E_EDGES 800000
#define ET (E_EDGES + N_NODES)

typedef _Float16 h8 __attribute__((ext_vector_type(8)));
typedef float f32x16 __attribute__((ext_vector_type(16)));

__device__ __forceinline__ float lrelu(float v) { return v > 0.f ? v : 0.2f * v; }

// ---------- prep: x->fp16, W1/W2->fp16, zero-pad, sharded degree histogram ----------
__global__ __launch_bounds__(256) void prep_kernel(const float* __restrict__ x,
                                                   const int* __restrict__ ei,
                                                   const float* __restrict__ W1,
                                                   const float* __restrict__ W2,
                                                   _Float16* __restrict__ xh,
                                                   _Float16* __restrict__ w1h,
                                                   _Float16* __restrict__ w2h,
                                                   int* __restrict__ deg4) {
    int i = blockIdx.x * 256 + threadIdx.x;
    if (i < 1600000) {
        const float4* x4 = (const float4*)x;
        float4 a = x4[(size_t)i * 2], b = x4[(size_t)i * 2 + 1];
        h8 v;
        v[0] = (_Float16)a.x; v[1] = (_Float16)a.y; v[2] = (_Float16)a.z; v[3] = (_Float16)a.w;
        v[4] = (_Float16)b.x; v[5] = (_Float16)b.y; v[6] = (_Float16)b.z; v[7] = (_Float16)b.w;
        *(h8*)(xh + (size_t)i * 8) = v;
    } else if (i < 2400000) {
        int d = ei[E_EDGES + (i - 1600000)];
        atomicAdd(&deg4[(threadIdx.x & 3) * N_NODES + d], 1);
    } else if (i < 2404096) {
        int j = (i - 2400000) * 8;
#pragma unroll
        for (int t = 0; t < 8; t++) w1h[j + t] = (_Float16)W1[j + t];
    } else if (i < 2404608) {
        int j = (i - 2404096) * 8;
#pragma unroll
        for (int t = 0; t < 8; t++) w2h[j + t] = (_Float16)W2[j + t];
    } else if (i < 2405376) {
        int j = (i - 2404608) * 8;
#pragma unroll
        for (int t = 0; t < 8; t++) w1h[136 * 256 + j + t] = (_Float16)0.f;
    }
}

// ---------- Aw: rows 128..135 of w1h = attention-combined weights ----------
__global__ __launch_bounds__(256) void aw_kernel(const float* __restrict__ W1,
                                                 const float* __restrict__ as1,
                                                 const float* __restrict__ ad1,
                                                 _Float16* __restrict__ w1h) {
    int i = blockIdx.x * 256 + threadIdx.x;  // 0..2047
    int h = i >> 8, k = i & 255;
    const float* av = (h < 4 ? as1 : ad1) + (h & 3) * 32;
    const float* wb = W1 + (size_t)(h & 3) * 32 * 256 + k;
    float s = 0.f;
#pragma unroll
    for (int c = 0; c < 32; c++) s += av[c] * wb[(size_t)c * 256];
    w1h[(size_t)(128 + h) * 256 + k] = (_Float16)s;
}

// ---------- GEMM1 (MFMA): h1h[N,128] = xh @ w1h[0:128]^T ; cols 128..135 -> asc1/adc1 ----------
__global__ __launch_bounds__(256) void gemm1_mfma(const _Float16* __restrict__ xh,
                                                  const _Float16* __restrict__ w1h,
                                                  _Float16* __restrict__ h1h,
                                                  float* __restrict__ asc1,
                                                  float* __restrict__ adc1) {
    int wid = threadIdx.x >> 6, lane = threadIdx.x & 63;
    int rbase = blockIdx.x * 128 + wid * 32;
    if (rbase >= N_NODES) return;
    int l31 = lane & 31, l5 = lane >> 5;
    int ar = rbase + l31;
    if (ar > N_NODES - 1) ar = N_NODES - 1;
    const _Float16* ap = xh + (size_t)ar * 256 + l5 * 8;
    const _Float16* bp = w1h + (size_t)l31 * 256 + l5 * 8;
    f32x16 acc0 = {}, acc1 = {}, acc2 = {}, acc3 = {}, acc4 = {};
#pragma unroll 4
    for (int ks = 0; ks < 16; ks++) {
        h8 av = *(const h8*)(ap + ks * 16);
        h8 b0 = *(const h8*)(bp + ks * 16);
        h8 b1 = *(const h8*)(bp + 32 * 256 + ks * 16);
        h8 b2 = *(const h8*)(bp + 64 * 256 + ks * 16);
        h8 b3 = *(const h8*)(bp + 96 * 256 + ks * 16);
        h8 b4 = *(const h8*)(bp + 128 * 256 + ks * 16);
        acc0 = __builtin_amdgcn_mfma_f32_32x32x16_f16(av, b0, acc0, 0, 0, 0);
        acc1 = __builtin_amdgcn_mfma_f32_32x32x16_f16(av, b1, acc1, 0, 0, 0);
        acc2 = __builtin_amdgcn_mfma_f32_32x32x16_f16(av, b2, acc2, 0, 0, 0);
        acc3 = __builtin_amdgcn_mfma_f32_32x32x16_f16(av, b3, acc3, 0, 0, 0);
        acc4 = __builtin_amdgcn_mfma_f32_32x32x16_f16(av, b4, acc4, 0, 0, 0);
    }
#pragma unroll
    for (int j = 0; j < 16; j++) {
        int row = rbase + (j & 3) + 8 * (j >> 2) + 4 * l5;
        if (row < N_NODES) {
            h1h[(size_t)row * 128 + 0  + l31] = (_Float16)acc0[j];
            h1h[(size_t)row * 128 + 32 + l31] = (_Float16)acc1[j];
            h1h[(size_t)row * 128 + 64 + l31] = (_Float16)acc2[j];
            h1h[(size_t)row * 128 + 96 + l31] = (_Float16)acc3[j];
            float v4 = acc4[j];
            if (l31 < 4) asc1[(size_t)row * 4 + l31] = v4;
            else if (l31 < 8) adc1[(size_t)row * 4 + (l31 - 4)] = v4;
        }
    }
}

// ---------- device-wide scan of (deg+1), 3 stages ----------
__global__ __launch_bounds__(1024) void scanA_kernel(const int* __restrict__ deg4,
                                                     int* __restrict__ off,
                                                     int* __restrict__ bsum) {
    __shared__ int s[1024];
    int t = threadIdx.x;
    int n = blockIdx.x * 1024 + t;
    int v = 0;
    if (n < N_NODES) {
        v = 1 + deg4[n] + deg4[N_NODES + n] + deg4[2 * N_NODES + n] + deg4[3 * N_NODES + n];
    }
    s[t] = v;
    __syncthreads();
    for (int d = 1; d < 1024; d <<= 1) {
        int u = (t >= d) ? s[t - d] : 0;
        __syncthreads();
        s[t] += u;
        __syncthreads();
    }
    if (n < N_NODES) off[n] = s[t] - v;
    if (t == 1023) bsum[blockIdx.x] = s[1023];
}

__global__ void scanB_kernel(int* __restrict__ bsum) {
    int t = threadIdx.x;  // 64 threads, 1 wave
    int v = (t < 49) ? bsum[t] : 0;
#pragma unroll
    for (int d = 1; d < 64; d <<= 1) {
        int u = __shfl_up(v, d);
        if (t >= d) v += u;
    }
    if (t < 49) bsum[t] = v;
}

__global__ __launch_bounds__(1024) void scanC_kernel(const int* __restrict__ bsum,
                                                     int* __restrict__ off,
                                                     int* __restrict__ cursor) {
    int b = blockIdx.x;
    int base = (b == 0) ? 0 : bsum[b - 1];
    int n = b * 1024 + threadIdx.x;
    if (n < N_NODES) {
        int o = off[n] + base;
        off[n] = o;
        cursor[n] = o;
    }
    if (n == 0) off[N_NODES] = ET;
}

// ---------- fill CSR: one 16B AoS record per edge {src, 0, half4 p1} ----------
__global__ void fill_kernel(const int* __restrict__ ei, int* __restrict__ cursor,
                            const float* __restrict__ asc1, const float* __restrict__ adc1,
                            int4* __restrict__ combo) {
    int i = blockIdx.x * blockDim.x + threadIdx.x;
    if (i >= ET) return;
    int s, d;
    if (i < E_EDGES) { s = ei[i]; d = ei[E_EDGES + i]; }
    else { s = i - E_EDGES; d = s; }
    int pos = atomicAdd(&cursor[d], 1);
    float4 av = *(const float4*)(asc1 + (size_t)s * 4);
    float4 dv = *(const float4*)(adc1 + (size_t)d * 4);
    __half2 p01 = __floats2half2_rn(__expf(lrelu(av.x + dv.x)), __expf(lrelu(av.y + dv.y)));
    __half2 p23 = __floats2half2_rn(__expf(lrelu(av.z + dv.z)), __expf(lrelu(av.w + dv.w)));
    int4 rec;
    rec.x = s;
    rec.y = *(int*)&p01;
    rec.z = *(int*)&p23;
    rec.w = 0;
    combo[pos] = rec;
}

// ---------- Layer-1 aggregation (wave per dst node) ----------
__global__ __launch_bounds__(256) void agg1_kernel(const __half* __restrict__ h1h,
                                                   const int4* __restrict__ combo,
                                                   const float* __restrict__ b1,
                                                   const int* __restrict__ off,
                                                   __half* __restrict__ h1b) {
    int wid = threadIdx.x >> 6, lane = threadIdx.x & 63;
    int node = blockIdx.x * 4 + wid;
    if (node >= N_NODES) return;
    int hh = lane >> 4;
    const __half2* h1h2 = (const __half2*)h1h;
    int s0 = off[node], s1 = off[node + 1];
    float den = 0.f, a0 = 0.f, a1 = 0.f;
    int j = s0;
    for (; j + 4 <= s1; j += 4) {
        int4 cA = combo[j], cB = combo[j + 1], cC = combo[j + 2], cD = combo[j + 3];
        union { int u; __half2 h; } vA, vB, vC, vD;
        vA.u = (hh & 2) ? cA.z : cA.y;
        vB.u = (hh & 2) ? cB.z : cB.y;
        vC.u = (hh & 2) ? cC.z : cC.y;
        vD.u = (hh & 2) ? cD.z : cD.y;
        float pA = __half2float((hh & 1) ? vA.h.y : vA.h.x);
        float pB = __half2float((hh & 1) ? vB.h.y : vB.h.x);
        float pC = __half2float((hh & 1) ? vC.h.y : vC.h.x);
        float pD = __half2float((hh & 1) ? vD.h.y : vD.h.x);
        __half2 hA = h1h2[(size_t)cA.x * 64 + lane];
        __half2 hB = h1h2[(size_t)cB.x * 64 + lane];
        __half2 hC = h1h2[(size_t)cC.x * 64 + lane];
        __half2 hD = h1h2[(size_t)cD.x * 64 + lane];
        den += (pA + pB) + (pC + pD);
        float2 fA = __half22float2(hA), fB = __half22float2(hB);
        float2 fC = __half22float2(hC), fD = __half22float2(hD);
        a0 += pA * fA.x + pB * fB.x + pC * fC.x + pD * fD.x;
        a1 += pA * fA.y + pB * fB.y + pC * fC.y + pD * fD.y;
    }
    for (; j < s1; j++) {
        int4 c = combo[j];
        union { int u; __half2 h; } v;
        v.u = (hh & 2) ? c.z : c.y;
        float p = __half2float((hh & 1) ? v.h.y : v.h.x);
        float2 f = __half22float2(h1h2[(size_t)c.x * 64 + lane]);
        den += p;
        a0 += p * f.x;
        a1 += p * f.y;
    }
    float inv = 1.f / (den + 1e-16f);
    float o0 = fmaxf(a0 * inv + b1[2 * lane], 0.f);
    float o1 = fmaxf(a1 * inv + b1[2 * lane + 1], 0.f);
    ((__half2*)h1b)[(size_t)node * 64 + lane] = __floats2half2_rn(o0, o1);
}

// ---------- GEMM2 (MFMA): h2h[N,32] = h1b @ w2h^T ; epilogue asc2/adc2 ----------
__global__ __launch_bounds__(256) void gemm2_mfma(const __half* __restrict__ h1b,
                                                  const _Float16* __restrict__ w2h,
                                                  const float* __restrict__ as2,
                                                  const float* __restrict__ ad2,
                                                  __half* __restrict__ h2h,
                                                  float* __restrict__ asc2,
                                                  float* __restrict__ adc2) {
    int wid = threadIdx.x >> 6, lane = threadIdx.x & 63;
    int rbase = blockIdx.x * 128 + wid * 32;
    if (rbase >= N_NODES) return;
    int l31 = lane & 31, l5 = lane >> 5;
    int ar = rbase + l31;
    if (ar > N_NODES - 1) ar = N_NODES - 1;
    const _Float16* ap = (const _Float16*)h1b + (size_t)ar * 128 + l5 * 8;
    const _Float16* bp = w2h + (size_t)l31 * 128 + l5 * 8;
    f32x16 acc = {};
#pragma unroll
    for (int ks = 0; ks < 8; ks++) {
        h8 av = *(const h8*)(ap + ks * 16);
        h8 bv = *(const h8*)(bp + ks * 16);
        acc = __builtin_amdgcn_mfma_f32_32x32x16_f16(av, bv, acc, 0, 0, 0);
    }
    float asw = as2[l31], adw = ad2[l31];
#pragma unroll
    for (int j = 0; j < 16; j++) {
        int row = rbase + (j & 3) + 8 * (j >> 2) + 4 * l5;
        float v = acc[j];
        float sv = v * asw, dv = v * adw;
#pragma unroll
        for (int m = 1; m <= 16; m <<= 1) {
            sv += __shfl_xor(sv, m);
            dv += __shfl_xor(dv, m);
        }
        if (row < N_NODES) {
            h2h[(size_t)row * 32 + l31] = __float2half(v);
            if (l31 == 0) { asc2[row] = sv; adc2[row] = dv; }
        }
    }
}

// ---------- Layer-2 aggregation + log_softmax (p2 computed on the fly) ----------
__global__ __launch_bounds__(256) void agg2_kernel(const __half* __restrict__ h2h,
                                                   const int4* __restrict__ combo,
                                                   const float* __restrict__ asc2,
                                                   const float* __restrict__ adc2,
                                                   const float* __restrict__ b2,
                                                   const int* __restrict__ off,
                                                   float* __restrict__ out) {
    int wid = threadIdx.x >> 6, lane = threadIdx.x & 63;
    int node = blockIdx.x * 4 + wid;
    if (node >= N_NODES) return;
    int g = lane >> 4;
    int li = lane & 15;
    const __half2* h2h2 = (const __half2*)h2h;
    float adv = adc2[node];
    int s0 = off[node], s1 = off[node + 1];
    float den = 0.f, a0 = 0.f, a1 = 0.f;
    int j = s0 + g;
    for (; j + 8 <= s1; j += 8) {
        int sA = combo[j].x, sB = combo[j + 4].x;
        float pA = __expf(lrelu(asc2[sA] + adv));
        float pB = __expf(lrelu(asc2[sB] + adv));
        float2 fA = __half22float2(h2h2[(size_t)sA * 16 + li]);
        float2 fB = __half22float2(h2h2[(size_t)sB * 16 + li]);
        den += pA + pB;
        a0 += pA * fA.x + pB * fB.x;
        a1 += pA * fA.y + pB * fB.y;
    }
    for (; j < s1; j += 4) {
        int s = combo[j].x;
        float p = __expf(lrelu(asc2[s] + adv));
        float2 f = __half22float2(h2h2[(size_t)s * 16 + li]);
        den += p;
        a0 += p * f.x;
        a1 += p * f.y;
    }
    den += __shfl_xor(den, 16); den += __shfl_xor(den, 32);
    a0 += __shfl_xor(a0, 16);  a0 += __shfl_xor(a0, 32);
    a1 += __shfl_xor(a1, 16);  a1 += __shfl_xor(a1, 32);
    float inv = 1.f / (den + 1e-16f);
    float v0 = a0 * inv + b2[2 * li];
    float v1 = a1 * inv + b2[2 * li + 1];
    float mx = fmaxf(v0, v1);
#pragma unroll
    for (int msk = 8; msk >= 1; msk >>= 1) mx = fmaxf(mx, __shfl_xor(mx, msk));
    float se = __expf(v0 - mx) + __expf(v1 - mx);
#pragma unroll
    for (int msk = 8; msk >= 1; msk >>= 1) se += __shfl_xor(se, msk);
    float lse = mx + __logf(se);
    if (lane < 16) {
        ((float2*)out)[(size_t)node * 16 + li] = make_float2(v0 - lse, v1 - lse);
    }
}

extern "C" void kernel_launch(void* const* d_in, const int* in_sizes, int n_in,
                              void* d_out, int out_size, void* d_ws, size_t ws_size,
                              hipStream_t stream) {
    const float* x   = (const float*)d_in[0];
    const int* ei    = (const int*)d_in[1];
    const float* W1  = (const float*)d_in[2];
    const float* as1 = (const float*)d_in[3];
    const float* ad1 = (const float*)d_in[4];
    const float* b1  = (const float*)d_in[5];
    const float* W2  = (const float*)d_in[6];
    const float* as2 = (const float*)d_in[7];
    const float* ad2 = (const float*)d_in[8];
    const float* b2  = (const float*)d_in[9];
    float* out = (float*)d_out;

    char* base = (char*)d_ws;
    // Region X [0, 25,600,000): xh during prep/gemm1; combo (13.6MB) after gemm1
    _Float16* xh  = (_Float16*)base;
    int4* combo   = (int4*)base;                       // ET*16 = 13,600,000
    _Float16* w1h = (_Float16*)(base + 25600000);      // 160*256*2 = 81,920
    _Float16* w2h = (_Float16*)(base + 25681920);      // 8,192
    _Float16* h1h = (_Float16*)(base + 25690112);      // 12,800,000
    __half* h1b   = (__half*)(base + 38490112);        // 12,800,000
    __half* h2h   = (__half*)(base + 51290112);        //  3,200,000
    float* asc1   = (float*)(base + 54490112);         //    800,000
    float* adc1   = (float*)(base + 55290112);         //    800,000
    float* asc2   = (float*)(base + 56090112);         //    200,000
    float* adc2   = (float*)(base + 56290112);         //    200,000
    int* deg4     = (int*)(base + 56490112);           //    800,000 (4 shards)
    int* off      = (int*)(base + 57290112);           //    200,004
    int* cursor   = (int*)(base + 57490116);           //    200,004
    int* bsum     = (int*)(base + 57690120);           //        256

    hipMemsetAsync(deg4, 0, 4 * N_NODES * sizeof(int), stream);

    prep_kernel<<<9396, 256, 0, stream>>>(x, ei, W1, W2, xh, w1h, w2h, deg4);
    aw_kernel<<<8, 256, 0, stream>>>(W1, as1, ad1, w1h);
    gemm1_mfma<<<391, 256, 0, stream>>>(xh, w1h, h1h, asc1, adc1);
    scanA_kernel<<<49, 1024, 0, stream>>>(deg4, off, bsum);
    scanB_kernel<<<1, 64, 0, stream>>>(bsum);
    scanC_kernel<<<49, 1024, 0, stream>>>(bsum, off, cursor);
    fill_kernel<<<(ET + 255) / 256, 256, 0, stream>>>(ei, cursor, asc1, adc1, combo);
    agg1_kernel<<<(N_NODES + 3) / 4, 256, 0, stream>>>((const __half*)h1h, combo, b1, off, h1b);
    gemm2_mfma<<<391, 256, 0, stream>>>(h1b, w2h, as2, ad2, h2h, asc2, adc2);
    agg2_kernel<<<(N_NODES + 3) / 4, 256, 0, stream>>>(h2h, combo, asc2, adc2, b2, off, out);
}

// Round 6
// 203.834 us; speedup vs baseline: 3.1293x; 1.0308x over previous
//
#include <hip/hip_runtime.h>
#include <hip/hip_fp16.h>

#define N_NODES 50000
#define E_EDGES 800000
#define ET (E_EDGES + N_NODES)

typedef _Float16 h8 __attribute__((ext_vector_type(8)));
typedef float f32x16 __attribute__((ext_vector_type(16)));

__device__ __forceinline__ float lrelu(float v) { return v > 0.f ? v : 0.2f * v; }

// ---------- prep: degree histogram + W1/W2 fp16 conversion (x conversion fused into gemm1) ----------
__global__ __launch_bounds__(256) void prep_kernel(const int* __restrict__ ei,
                                                   const float* __restrict__ W1,
                                                   const float* __restrict__ W2,
                                                   _Float16* __restrict__ w1h,
                                                   _Float16* __restrict__ w2h,
                                                   int* __restrict__ deg4) {
    int i = blockIdx.x * 256 + threadIdx.x;
    if (i < E_EDGES) {
        int d = ei[E_EDGES + i];
        atomicAdd(&deg4[(threadIdx.x & 3) * N_NODES + d], 1);
    } else if (i < E_EDGES + 4096) {
        int j = (i - E_EDGES) * 8;
#pragma unroll
        for (int t = 0; t < 8; t++) w1h[j + t] = (_Float16)W1[j + t];
    } else if (i < E_EDGES + 4608) {
        int j = (i - (E_EDGES + 4096)) * 8;
#pragma unroll
        for (int t = 0; t < 8; t++) w2h[j + t] = (_Float16)W2[j + t];
    } else if (i < E_EDGES + 5376) {
        int j = (i - (E_EDGES + 4608)) * 8;
#pragma unroll
        for (int t = 0; t < 8; t++) w1h[136 * 256 + j + t] = (_Float16)0.f;
    }
}

// ---------- Aw: rows 128..135 of w1h = attention-combined weights ----------
__global__ __launch_bounds__(256) void aw_kernel(const float* __restrict__ W1,
                                                 const float* __restrict__ as1,
                                                 const float* __restrict__ ad1,
                                                 _Float16* __restrict__ w1h) {
    int i = blockIdx.x * 256 + threadIdx.x;  // 0..2047
    int h = i >> 8, k = i & 255;
    const float* av = (h < 4 ? as1 : ad1) + (h & 3) * 32;
    const float* wb = W1 + (size_t)(h & 3) * 32 * 256 + k;
    float s = 0.f;
#pragma unroll
    for (int c = 0; c < 32; c++) s += av[c] * wb[(size_t)c * 256];
    w1h[(size_t)(128 + h) * 256 + k] = (_Float16)s;
}

// ---------- GEMM1 (MFMA): h1h[N,128] = cvt(x) @ w1h[0:128]^T ; cols 128..135 -> asc1/adc1 ----------
__global__ __launch_bounds__(256) void gemm1_mfma(const float* __restrict__ x,
                                                  const _Float16* __restrict__ w1h,
                                                  _Float16* __restrict__ h1h,
                                                  float* __restrict__ asc1,
                                                  float* __restrict__ adc1) {
    int wid = threadIdx.x >> 6, lane = threadIdx.x & 63;
    int rbase = blockIdx.x * 128 + wid * 32;
    if (rbase >= N_NODES) return;
    int l31 = lane & 31, l5 = lane >> 5;
    int ar = rbase + l31;
    if (ar > N_NODES - 1) ar = N_NODES - 1;
    const float* ap = x + (size_t)ar * 256 + l5 * 8;
    const _Float16* bp = w1h + (size_t)l31 * 256 + l5 * 8;
    f32x16 acc0 = {}, acc1 = {}, acc2 = {}, acc3 = {}, acc4 = {};
#pragma unroll 4
    for (int ks = 0; ks < 16; ks++) {
        float4 xa = *(const float4*)(ap + ks * 16);
        float4 xb = *(const float4*)(ap + ks * 16 + 4);
        h8 av;
        av[0] = (_Float16)xa.x; av[1] = (_Float16)xa.y;
        av[2] = (_Float16)xa.z; av[3] = (_Float16)xa.w;
        av[4] = (_Float16)xb.x; av[5] = (_Float16)xb.y;
        av[6] = (_Float16)xb.z; av[7] = (_Float16)xb.w;
        h8 b0 = *(const h8*)(bp + ks * 16);
        h8 b1 = *(const h8*)(bp + 32 * 256 + ks * 16);
        h8 b2 = *(const h8*)(bp + 64 * 256 + ks * 16);
        h8 b3 = *(const h8*)(bp + 96 * 256 + ks * 16);
        h8 b4 = *(const h8*)(bp + 128 * 256 + ks * 16);
        acc0 = __builtin_amdgcn_mfma_f32_32x32x16_f16(av, b0, acc0, 0, 0, 0);
        acc1 = __builtin_amdgcn_mfma_f32_32x32x16_f16(av, b1, acc1, 0, 0, 0);
        acc2 = __builtin_amdgcn_mfma_f32_32x32x16_f16(av, b2, acc2, 0, 0, 0);
        acc3 = __builtin_amdgcn_mfma_f32_32x32x16_f16(av, b3, acc3, 0, 0, 0);
        acc4 = __builtin_amdgcn_mfma_f32_32x32x16_f16(av, b4, acc4, 0, 0, 0);
    }
#pragma unroll
    for (int j = 0; j < 16; j++) {
        int row = rbase + (j & 3) + 8 * (j >> 2) + 4 * l5;
        if (row < N_NODES) {
            h1h[(size_t)row * 128 + 0  + l31] = (_Float16)acc0[j];
            h1h[(size_t)row * 128 + 32 + l31] = (_Float16)acc1[j];
            h1h[(size_t)row * 128 + 64 + l31] = (_Float16)acc2[j];
            h1h[(size_t)row * 128 + 96 + l31] = (_Float16)acc3[j];
            float v4 = acc4[j];
            if (l31 < 4) asc1[(size_t)row * 4 + l31] = v4;
            else if (l31 < 8) adc1[(size_t)row * 4 + (l31 - 4)] = v4;
        }
    }
}

// ---------- device-wide scan of (deg+1), 3 stages ----------
__global__ __launch_bounds__(1024) void scanA_kernel(const int* __restrict__ deg4,
                                                     int* __restrict__ off,
                                                     int* __restrict__ bsum) {
    __shared__ int s[1024];
    int t = threadIdx.x;
    int n = blockIdx.x * 1024 + t;
    int v = 0;
    if (n < N_NODES) {
        v = 1 + deg4[n] + deg4[N_NODES + n] + deg4[2 * N_NODES + n] + deg4[3 * N_NODES + n];
    }
    s[t] = v;
    __syncthreads();
    for (int d = 1; d < 1024; d <<= 1) {
        int u = (t >= d) ? s[t - d] : 0;
        __syncthreads();
        s[t] += u;
        __syncthreads();
    }
    if (n < N_NODES) off[n] = s[t] - v;
    if (t == 1023) bsum[blockIdx.x] = s[1023];
}

__global__ void scanB_kernel(int* __restrict__ bsum) {
    int t = threadIdx.x;  // 64 threads, 1 wave
    int v = (t < 49) ? bsum[t] : 0;
#pragma unroll
    for (int d = 1; d < 64; d <<= 1) {
        int u = __shfl_up(v, d);
        if (t >= d) v += u;
    }
    if (t < 49) bsum[t] = v;
}

__global__ __launch_bounds__(1024) void scanC_kernel(const int* __restrict__ bsum,
                                                     int* __restrict__ off,
                                                     int* __restrict__ cursor) {
    int b = blockIdx.x;
    int base = (b == 0) ? 0 : bsum[b - 1];
    int n = b * 1024 + threadIdx.x;
    if (n < N_NODES) {
        int o = off[n] + base;
        off[n] = o;
        cursor[n] = o;
    }
    if (n == 0) off[N_NODES] = ET;
}

// ---------- fill CSR: one 16B AoS record per edge {src, half4 p1, 0} ----------
__global__ void fill_kernel(const int* __restrict__ ei, int* __restrict__ cursor,
                            const float* __restrict__ asc1, const float* __restrict__ adc1,
                            int4* __restrict__ combo) {
    int i = blockIdx.x * blockDim.x + threadIdx.x;
    if (i >= ET) return;
    int s, d;
    if (i < E_EDGES) { s = ei[i]; d = ei[E_EDGES + i]; }
    else { s = i - E_EDGES; d = s; }
    int pos = atomicAdd(&cursor[d], 1);
    float4 av = *(const float4*)(asc1 + (size_t)s * 4);
    float4 dv = *(const float4*)(adc1 + (size_t)d * 4);
    __half2 p01 = __floats2half2_rn(__expf(lrelu(av.x + dv.x)), __expf(lrelu(av.y + dv.y)));
    __half2 p23 = __floats2half2_rn(__expf(lrelu(av.z + dv.z)), __expf(lrelu(av.w + dv.w)));
    int4 rec;
    rec.x = s;
    rec.y = *(int*)&p01;
    rec.z = *(int*)&p23;
    rec.w = 0;
    combo[pos] = rec;
}

// ---------- Layer-1 aggregation (wave per dst node, 8 gathers in flight) ----------
__global__ __launch_bounds__(256) void agg1_kernel(const __half* __restrict__ h1h,
                                                   const int4* __restrict__ combo,
                                                   const float* __restrict__ b1,
                                                   const int* __restrict__ off,
                                                   __half* __restrict__ h1b) {
    int wid = threadIdx.x >> 6, lane = threadIdx.x & 63;
    int node = blockIdx.x * 4 + wid;
    if (node >= N_NODES) return;
    int hh = lane >> 4;
    const __half2* h1h2 = (const __half2*)h1h;
    int s0 = off[node], s1 = off[node + 1];
    float den = 0.f, a0 = 0.f, a1 = 0.f;
    int j = s0;
    for (; j + 8 <= s1; j += 8) {
        int4 c[8];
#pragma unroll
        for (int u = 0; u < 8; u++) c[u] = combo[j + u];
        __half2 hv[8];
#pragma unroll
        for (int u = 0; u < 8; u++) hv[u] = h1h2[(size_t)c[u].x * 64 + lane];
#pragma unroll
        for (int u = 0; u < 8; u++) {
            union { int u32; __half2 h; } v;
            v.u32 = (hh & 2) ? c[u].z : c[u].y;
            float p = __half2float((hh & 1) ? v.h.y : v.h.x);
            float2 f = __half22float2(hv[u]);
            den += p;
            a0 += p * f.x;
            a1 += p * f.y;
        }
    }
    for (; j + 4 <= s1; j += 4) {
        int4 c[4];
#pragma unroll
        for (int u = 0; u < 4; u++) c[u] = combo[j + u];
        __half2 hv[4];
#pragma unroll
        for (int u = 0; u < 4; u++) hv[u] = h1h2[(size_t)c[u].x * 64 + lane];
#pragma unroll
        for (int u = 0; u < 4; u++) {
            union { int u32; __half2 h; } v;
            v.u32 = (hh & 2) ? c[u].z : c[u].y;
            float p = __half2float((hh & 1) ? v.h.y : v.h.x);
            float2 f = __half22float2(hv[u]);
            den += p;
            a0 += p * f.x;
            a1 += p * f.y;
        }
    }
    for (; j < s1; j++) {
        int4 c = combo[j];
        union { int u32; __half2 h; } v;
        v.u32 = (hh & 2) ? c.z : c.y;
        float p = __half2float((hh & 1) ? v.h.y : v.h.x);
        float2 f = __half22float2(h1h2[(size_t)c.x * 64 + lane]);
        den += p;
        a0 += p * f.x;
        a1 += p * f.y;
    }
    float inv = 1.f / (den + 1e-16f);
    float o0 = fmaxf(a0 * inv + b1[2 * lane], 0.f);
    float o1 = fmaxf(a1 * inv + b1[2 * lane + 1], 0.f);
    ((__half2*)h1b)[(size_t)node * 64 + lane] = __floats2half2_rn(o0, o1);
}

// ---------- GEMM2 (MFMA): h2h[N,32] = h1b @ w2h^T ; epilogue asc2/adc2 ----------
__global__ __launch_bounds__(256) void gemm2_mfma(const __half* __restrict__ h1b,
                                                  const _Float16* __restrict__ w2h,
                                                  const float* __restrict__ as2,
                                                  const float* __restrict__ ad2,
                                                  __half* __restrict__ h2h,
                                                  float* __restrict__ asc2,
                                                  float* __restrict__ adc2) {
    int wid = threadIdx.x >> 6, lane = threadIdx.x & 63;
    int rbase = blockIdx.x * 128 + wid * 32;
    if (rbase >= N_NODES) return;
    int l31 = lane & 31, l5 = lane >> 5;
    int ar = rbase + l31;
    if (ar > N_NODES - 1) ar = N_NODES - 1;
    const _Float16* ap = (const _Float16*)h1b + (size_t)ar * 128 + l5 * 8;
    const _Float16* bp = w2h + (size_t)l31 * 128 + l5 * 8;
    f32x16 acc = {};
#pragma unroll
    for (int ks = 0; ks < 8; ks++) {
        h8 av = *(const h8*)(ap + ks * 16);
        h8 bv = *(const h8*)(bp + ks * 16);
        acc = __builtin_amdgcn_mfma_f32_32x32x16_f16(av, bv, acc, 0, 0, 0);
    }
    float asw = as2[l31], adw = ad2[l31];
#pragma unroll
    for (int j = 0; j < 16; j++) {
        int row = rbase + (j & 3) + 8 * (j >> 2) + 4 * l5;
        float v = acc[j];
        float sv = v * asw, dv = v * adw;
#pragma unroll
        for (int m = 1; m <= 16; m <<= 1) {
            sv += __shfl_xor(sv, m);
            dv += __shfl_xor(dv, m);
        }
        if (row < N_NODES) {
            h2h[(size_t)row * 32 + l31] = __float2half(v);
            if (l31 == 0) { asc2[row] = sv; adc2[row] = dv; }
        }
    }
}

// ---------- Layer-2 aggregation + log_softmax (p2 on the fly, 4 gathers in flight) ----------
__global__ __launch_bounds__(256) void agg2_kernel(const __half* __restrict__ h2h,
                                                   const int4* __restrict__ combo,
                                                   const float* __restrict__ asc2,
                                                   const float* __restrict__ adc2,
                                                   const float* __restrict__ b2,
                                                   const int* __restrict__ off,
                                                   float* __restrict__ out) {
    int wid = threadIdx.x >> 6, lane = threadIdx.x & 63;
    int node = blockIdx.x * 4 + wid;
    if (node >= N_NODES) return;
    int g = lane >> 4;
    int li = lane & 15;
    const __half2* h2h2 = (const __half2*)h2h;
    float adv = adc2[node];
    int s0 = off[node], s1 = off[node + 1];
    float den = 0.f, a0 = 0.f, a1 = 0.f;
    int j = s0 + g;
    for (; j + 16 <= s1; j += 16) {
        int s[4];
#pragma unroll
        for (int u = 0; u < 4; u++) s[u] = combo[j + 4 * u].x;
        float av[4];
#pragma unroll
        for (int u = 0; u < 4; u++) av[u] = asc2[s[u]];
        __half2 hv[4];
#pragma unroll
        for (int u = 0; u < 4; u++) hv[u] = h2h2[(size_t)s[u] * 16 + li];
#pragma unroll
        for (int u = 0; u < 4; u++) {
            float p = __expf(lrelu(av[u] + adv));
            float2 f = __half22float2(hv[u]);
            den += p;
            a0 += p * f.x;
            a1 += p * f.y;
        }
    }
    for (; j < s1; j += 4) {
        int s = combo[j].x;
        float p = __expf(lrelu(asc2[s] + adv));
        float2 f = __half22float2(h2h2[(size_t)s * 16 + li]);
        den += p;
        a0 += p * f.x;
        a1 += p * f.y;
    }
    den += __shfl_xor(den, 16); den += __shfl_xor(den, 32);
    a0 += __shfl_xor(a0, 16);  a0 += __shfl_xor(a0, 32);
    a1 += __shfl_xor(a1, 16);  a1 += __shfl_xor(a1, 32);
    float inv = 1.f / (den + 1e-16f);
    float v0 = a0 * inv + b2[2 * li];
    float v1 = a1 * inv + b2[2 * li + 1];
    float mx = fmaxf(v0, v1);
#pragma unroll
    for (int msk = 8; msk >= 1; msk >>= 1) mx = fmaxf(mx, __shfl_xor(mx, msk));
    float se = __expf(v0 - mx) + __expf(v1 - mx);
#pragma unroll
    for (int msk = 8; msk >= 1; msk >>= 1) se += __shfl_xor(se, msk);
    float lse = mx + __logf(se);
    if (lane < 16) {
        ((float2*)out)[(size_t)node * 16 + li] = make_float2(v0 - lse, v1 - lse);
    }
}

extern "C" void kernel_launch(void* const* d_in, const int* in_sizes, int n_in,
                              void* d_out, int out_size, void* d_ws, size_t ws_size,
                              hipStream_t stream) {
    const float* x   = (const float*)d_in[0];
    const int* ei    = (const int*)d_in[1];
    const float* W1  = (const float*)d_in[2];
    const float* as1 = (const float*)d_in[3];
    const float* ad1 = (const float*)d_in[4];
    const float* b1  = (const float*)d_in[5];
    const float* W2  = (const float*)d_in[6];
    const float* as2 = (const float*)d_in[7];
    const float* ad2 = (const float*)d_in[8];
    const float* b2  = (const float*)d_in[9];
    float* out = (float*)d_out;

    char* base = (char*)d_ws;
    int4* combo   = (int4*)base;                       // ET*16 = 13,600,000
    _Float16* w1h = (_Float16*)(base + 25600000);      // 160*256*2 = 81,920
    _Float16* w2h = (_Float16*)(base + 25681920);      // 8,192
    _Float16* h1h = (_Float16*)(base + 25690112);      // 12,800,000
    __half* h1b   = (__half*)(base + 38490112);        // 12,800,000
    __half* h2h   = (__half*)(base + 51290112);        //  3,200,000
    float* asc1   = (float*)(base + 54490112);         //    800,000
    float* adc1   = (float*)(base + 55290112);         //    800,000
    float* asc2   = (float*)(base + 56090112);         //    200,000
    float* adc2   = (float*)(base + 56290112);         //    200,000
    int* deg4     = (int*)(base + 56490112);           //    800,000 (4 shards)
    int* off      = (int*)(base + 57290112);           //    200,004
    int* cursor   = (int*)(base + 57490116);           //    200,004
    int* bsum     = (int*)(base + 57690120);           //        256

    hipMemsetAsync(deg4, 0, 4 * N_NODES * sizeof(int), stream);

    prep_kernel<<<(E_EDGES + 5376 + 255) / 256, 256, 0, stream>>>(ei, W1, W2, w1h, w2h, deg4);
    aw_kernel<<<8, 256, 0, stream>>>(W1, as1, ad1, w1h);
    gemm1_mfma<<<391, 256, 0, stream>>>(x, w1h, h1h, asc1, adc1);
    scanA_kernel<<<49, 1024, 0, stream>>>(deg4, off, bsum);
    scanB_kernel<<<1, 64, 0, stream>>>(bsum);
    scanC_kernel<<<49, 1024, 0, stream>>>(bsum, off, cursor);
    fill_kernel<<<(ET + 255) / 256, 256, 0, stream>>>(ei, cursor, asc1, adc1, combo);
    agg1_kernel<<<(N_NODES + 3) / 4, 256, 0, stream>>>((const __half*)h1h, combo, b1, off, h1b);
    gemm2_mfma<<<391, 256, 0, stream>>>(h1b, w2h, as2, ad2, h2h, asc2, adc2);
    agg2_kernel<<<(N_NODES + 3) / 4, 256, 0, stream>>>(h2h, combo, asc2, adc2, b2, off, out);
}